// Round 11
// baseline (691.015 us; speedup 1.0000x reference)
//
#include <hip/hip_runtime.h>
#include <math.h>

namespace {

constexpr int Bn=2, CIc=16, COc=16, Hc=256, Wc=256, HIDc=64, C5c=320;
constexpr int SPc = 4096;               // 64*64
constexpr float EPSc = 1e-5f;

// ---- 4x4 mean downsample: x (B,16,256,256) -> xd (B,16,64,64) ----
__global__ void k_down(const float* __restrict__ x, float* __restrict__ xd){
  int idx = blockIdx.x*blockDim.x + threadIdx.x;
  if (idx >= Bn*CIc*SPc) return;
  int q = idx & 63, p = (idx>>6)&63, c = idx>>12;
  const float* xp = x + ((size_t)c*Hc + p*4)*Wc + q*4;
  float s = 0.f;
  #pragma unroll
  for(int dy=0; dy<4; dy++)
    #pragma unroll
    for(int dx=0; dx<4; dx++) s += xp[dy*Wc+dx];
  xd[idx] = s * (1.f/16.f);
}

// ---- conv0 3x3 pad1 (16->64) + scalar PReLU ----
__global__ void k_conv0(const float* __restrict__ xd, const float* __restrict__ w,
                        const float* __restrict__ bias, const float* __restrict__ a0,
                        float* __restrict__ h){
  int idx = blockIdx.x*blockDim.x + threadIdx.x;
  if (idx >= Bn*HIDc*SPc) return;
  int q = idx&63, p=(idx>>6)&63, co=(idx>>12)&63, b=idx/(HIDc*SPc);
  float acc = bias[co];
  for(int ci=0; ci<CIc; ci++){
    const float* xp = xd + (size_t)(b*CIc+ci)*SPc;
    const float* wp = w + (co*CIc+ci)*9;
    #pragma unroll
    for(int u=0; u<3; u++){
      int pp = p+u-1; if((unsigned)pp >= 64u) continue;
      #pragma unroll
      for(int v=0; v<3; v++){
        int qq = q+v-1; if((unsigned)qq >= 64u) continue;
        acc = fmaf(xp[pp*64+qq], wp[u*3+v], acc);
      }
    }
  }
  float a = a0[0];
  h[idx] = acc >= 0.f ? acc : a*acc;
}

// ---- fused 1x1 conv 64->320 + stat partials ----
__global__ void k_c1(const float* __restrict__ h, const float* __restrict__ w,
                     const float* __restrict__ bias, float* __restrict__ t1,
                     float* __restrict__ pacc){
  __shared__ float lh[64*64];
  int og = blockIdx.x, sj = blockIdx.y, b = blockIdx.z;
  int tid = threadIdx.x;
  for(int it=0; it<4; ++it){
    int f4 = tid + it*256;               // c*16 + s4
    int c = f4>>4, s4 = f4&15;
    float4 v = *(const float4*)(h + (size_t)(b*64+c)*SPc + sj*64 + s4*4);
    *(float4*)(&lh[c*64 + s4*4]) = v;
  }
  __syncthreads();
  int osub = tid>>6, s = tid&63;
  int ob = og*40 + osub*10;
  float acc[10];
  #pragma unroll
  for(int j=0;j<10;j++) acc[j] = bias[ob+j];
  for(int c=0;c<64;c++){
    float hv = lh[c*64+s];
    #pragma unroll
    for(int j=0;j<10;j++) acc[j] = fmaf(hv, w[(ob+j)*64 + c], acc[j]);
  }
  #pragma unroll
  for(int j=0;j<10;j++){
    int o = ob+j;
    t1[(size_t)(b*320+o)*SPc + sj*64 + s] = acc[j];
    float sm = acc[j], sq = acc[j]*acc[j];
    #pragma unroll
    for(int d=1; d<64; d<<=1){ sm += __shfl_xor(sm,d); sq += __shfl_xor(sq,d); }
    if(s==0){
      pacc[o*128 + b*64 + sj]         = sm;   // P=128
      pacc[40960 + o*128 + b*64 + sj] = sq;   // CP = 320*128
    }
  }
}

// ---- finalize: partials -> fused BN scale/shift A,B (deterministic) ----
__global__ void k_fin(const float* __restrict__ pacc, int P, float invN,
                      const float* __restrict__ g, const float* __restrict__ bb,
                      float* __restrict__ A, float* __restrict__ B){
  __shared__ double sh[256], sh2[256];
  int c = blockIdx.x, C = gridDim.x, tid = threadIdx.x;
  double s=0.0, s2=0.0;
  for(int p=tid; p<P; p+=256){
    s  += (double)pacc[c*P+p];
    s2 += (double)pacc[C*P + c*P + p];
  }
  sh[tid]=s; sh2[tid]=s2; __syncthreads();
  for(int off=128; off>0; off>>=1){
    if(tid<off){ sh[tid]+=sh[tid+off]; sh2[tid]+=sh2[tid+off]; }
    __syncthreads();
  }
  if(tid==0){
    float m = (float)(sh[0]*(double)invN);
    float v = (float)(sh2[0]*(double)invN) - m*m;
    float r = rsqrtf(v + EPSc);
    float gc = g[c];
    A[c] = gc*r;
    B[c] = bb[c] - m*gc*r;
  }
}

// ---- depthwise 3x3 with BN1+PReLU1 on read + stat partials ----
__global__ void k_dw_s(const float* __restrict__ t1, const float* __restrict__ w,
                       const float* __restrict__ bias, const float* __restrict__ A,
                       const float* __restrict__ Bb, const float* __restrict__ ap,
                       float* __restrict__ t2, float* __restrict__ pacc){
  int idx = blockIdx.x*256 + threadIdx.x;
  int q = idx&63, p=(idx>>6)&63, c=(idx>>12)%C5c, b=idx/(C5c*SPc);
  float a1 = A[c], b1 = Bb[c], al = ap[0];
  const float* ip = t1 + (size_t)(b*C5c+c)*SPc;
  const float* wp = w + c*9;
  float acc = bias[c];
  #pragma unroll
  for(int u=0; u<3; u++){
    int pp = p+u-1; if((unsigned)pp >= 64u) continue;
    #pragma unroll
    for(int v=0; v<3; v++){
      int qq = q+v-1; if((unsigned)qq >= 64u) continue;
      float y = fmaf(ip[pp*64+qq], a1, b1);
      y = y >= 0.f ? y : al*y;
      acc = fmaf(y, wp[u*3+v], acc);
    }
  }
  t2[idx] = acc;
  float sm = acc, sq = acc*acc;
  #pragma unroll
  for(int d=1; d<64; d<<=1){ sm += __shfl_xor(sm,d); sq += __shfl_xor(sq,d); }
  __shared__ float sred[8];
  int wv = threadIdx.x>>6, ln = threadIdx.x&63;
  if(ln==0){ sred[wv]=sm; sred[4+wv]=sq; }
  __syncthreads();
  if(threadIdx.x==0){
    float S = ((sred[0]+sred[1])+(sred[2]+sred[3]));
    float Q = ((sred[4]+sred[5])+(sred[6]+sred[7]));
    int j = blockIdx.x & 15;
    pacc[c*32 + b*16 + j]         = S;   // P=32
    pacc[10240 + c*32 + b*16 + j] = Q;   // CP = 320*32
  }
}

// ---- fused 1x1 conv 320->64 with BN2+PReLU2 on read + stat partials ----
__global__ void k_c3(const float* __restrict__ t2, const float* __restrict__ w,
                     const float* __restrict__ bias, const float* __restrict__ A,
                     const float* __restrict__ Bb, const float* __restrict__ ap,
                     float* __restrict__ ts, float* __restrict__ pacc){
  __shared__ float li[80*16];     // 5 KB  [c80][s]
  __shared__ float lw[64*80];     // 20 KB [o][c80]
  int sjf = blockIdx.x, b = blockIdx.y, tid = threadIdx.x;
  float al = ap[0];
  int og = tid>>4, s = tid&15;
  float acc[4];
  #pragma unroll
  for(int j=0;j<4;j++) acc[j] = bias[og*4+j];

  for(int cc=0; cc<4; cc++){
    __syncthreads();
    {
      int t = tid;
      for(int r=0; r<2; ++r, t+=256){
        if(t < 320){
          int c = t>>2, k = t&3;
          int cg = cc*80 + c;
          float4 v = *(const float4*)(t2 + (size_t)(b*C5c+cg)*SPc + sjf*16 + k*4);
          float4 y;
          float a1 = A[cg], b1 = Bb[cg];
          y.x = fmaf(v.x, a1, b1); y.x = y.x>=0.f ? y.x : al*y.x;
          y.y = fmaf(v.y, a1, b1); y.y = y.y>=0.f ? y.y : al*y.y;
          y.z = fmaf(v.z, a1, b1); y.z = y.z>=0.f ? y.z : al*y.z;
          y.w = fmaf(v.w, a1, b1); y.w = y.w>=0.f ? y.w : al*y.w;
          *(float4*)(&li[c*16 + k*4]) = y;
        }
      }
    }
    for(int t = tid; t < 1280; t += 256){
      int o = t/20, k = t%20;
      float4 v = *(const float4*)(w + (size_t)o*C5c + cc*80 + k*4);
      *(float4*)(&lw[o*80 + k*4]) = v;
    }
    __syncthreads();
    for(int c=0; c<80; c++){
      float hv = li[c*16 + s];
      #pragma unroll
      for(int j=0;j<4;j++)
        acc[j] = fmaf(hv, lw[(og*4+j)*80 + c], acc[j]);
    }
  }

  #pragma unroll
  for(int j=0;j<4;j++){
    int o = og*4+j;
    ts[(size_t)(b*64+o)*SPc + sjf*16 + s] = acc[j];
    float sm = acc[j], sq = acc[j]*acc[j];
    #pragma unroll
    for(int d=1; d<16; d<<=1){ sm += __shfl_xor(sm,d); sq += __shfl_xor(sq,d); }
    if(s==0){
      pacc[o*512 + b*256 + sjf]         = sm;  // P=512
      pacc[32768 + o*512 + b*256 + sjf] = sq;  // CP = 64*512
    }
  }
}

// ---- BN3 + PReLU3 + residual add into h ----
__global__ void k_addres(const float* __restrict__ ts, float* __restrict__ h,
                         const float* __restrict__ A, const float* __restrict__ Bb,
                         const float* __restrict__ ap){
  int idx = blockIdx.x*256 + threadIdx.x;
  int c = (idx>>12)&63;
  float y = fmaf(ts[idx], A[c], Bb[c]);
  float al = ap[0];
  y = y >= 0.f ? y : al*y;
  h[idx] += y;
}

// ---- head 1x1 conv (64->512) writing z-innermost gvol, chunk=[k2][o16][z64] ----
// gv: [b][y=q(64)][x=ci(16)][k(2)][o(16)][z=p(64)]
__global__ void k_head_t(const float* __restrict__ h, const float* __restrict__ w,
                         const float* __restrict__ bias, float* __restrict__ gv){
  __shared__ float sb0[64*65], sb1[64*65];
  int bid = blockIdx.x;            // (b*16 + o)*16 + ci
  int ci = bid & 15, o = (bid>>4) & 15, b = bid >> 8;
  int c0 = (o*16 + ci)*2, c1 = c0 + 1;
  const float* hp0 = h + (size_t)b*HIDc*SPc;
  const float* w0 = w + (size_t)c0*HIDc;
  const float* w1 = w + (size_t)c1*HIDc;
  float b0 = bias[c0], b1 = bias[c1];
  int tid = threadIdx.x;
  for(int j=0; j<16; j++){
    int s = tid + j*256;           // s = p*64 + q
    float a0 = b0, a1 = b1;
    #pragma unroll 8
    for(int kc=0; kc<HIDc; kc++){
      float hv = hp0[kc*SPc + s];
      a0 = fmaf(hv, w0[kc], a0);
      a1 = fmaf(hv, w1[kc], a1);
    }
    int pad = s + (s>>6);
    sb0[pad] = a0; sb1[pad] = a1;
  }
  __syncthreads();
  float* gb = gv + (size_t)b*(64*16*2048);
  for(int j=0; j<16; j++){
    int t = tid + j*256;
    int q = t>>6, p = t&63;
    size_t base = ((size_t)(q*16 + ci))*2048 + (size_t)o*64 + p;
    gb[base]        = sb0[p*65 + q];   // k=0 weight plane
    gb[base + 1024] = sb1[p*65 + q];   // k=1 bias plane
  }
}

// ---- slice: block = 1 row x 16 cols, wave = 4px x 16o, o-stride 66 ----
// grid (16 xseg, 256 row, Bn), 256 thr, LDS 6 chunks x 2112 = 49.5 KB
__global__ void k_slice(const float* __restrict__ x, const float* __restrict__ gv,
                        float* __restrict__ outp, float* __restrict__ pacc){
  __shared__ float lds[6*2112];
  int xseg = blockIdx.x, hp = blockIdx.y, b = blockIdx.z;
  int tid = threadIdx.x;
  const float* gb = gv + (size_t)b*(64*16*2048);
  int y0 = (hp*63)/255;
  int y1 = min(y0+1, 63);
  int xbase = (xseg*16*15)/255;

  // stage 6 chunks (yi 0..1, xi 0..2); src chunk [k2][o16][z64], dst [k2][o*66+z]
  for(int t = tid; t < 6*512; t += 256){
    int cix = t >> 9, off = t & 511;
    int yi = cix/3, xi = cix - yi*3;
    int ys = yi ? y1 : y0;
    int xs = min(xbase + xi, 15);
    float4 v = *(const float4*)(gb + (((size_t)(ys*16+xs))<<11) + (size_t)off*4);
    int k  = off >> 8;
    int oz = (off & 255)*4;
    int o = oz >> 6, z = oz & 63;
    float* d = &lds[cix*2112 + k*1056 + o*66 + z];
    *(float2*)(d)   = make_float2(v.x, v.y);
    *(float2*)(d+2) = make_float2(v.z, v.w);
  }
  __syncthreads();

  int wv = tid>>6, lane = tid&63;
  int o = lane>>2, pl = lane&3;
  int lc = wv*4 + pl;
  int wq = xseg*16 + lc;

  float py = hp*(63.f/255.f);
  float fy = py - (float)y0;
  float pxv = wq*(15.f/255.f);
  int x0 = (wq*15)/255;
  float fx = pxv - (float)x0;
  int x1 = min(x0+1, 15);
  int xA = x0 - xbase, xB = x1 - xbase;
  int   cb[4]; float cw[4];
  cb[0] = (0*3+xA)*2112; cw[0] = (1.f-fy)*(1.f-fx);
  cb[1] = (0*3+xB)*2112; cw[1] = (1.f-fy)*fx;
  cb[2] = (1*3+xA)*2112; cw[2] = fy*(1.f-fx);
  cb[3] = (1*3+xB)*2112; cw[3] = fy*fx;

  int obase = o*66;
  float acc = 0.f, bacc = 0.f;
  for(int i=0; i<CIc; i++){
    float xv = x[((size_t)(b*CIc+i)*Hc + hp)*Wc + wq];
    float g = fminf(fmaxf(xv, 0.f), 1.f);
    float pz = g*63.f;
    int z0 = (int)pz; float fz = pz - (float)z0;
    int dz = (z0 < 63) ? 1 : 0;
    #pragma unroll
    for(int c4=0; c4<4; c4++){
      float w8 = cw[c4];
      float wz0 = w8*(1.f-fz), wz1 = w8*fz;
      int aw = cb[c4] + obase + z0;
      float w0v = lds[aw],      w1v = lds[aw+dz];
      float b0v = lds[aw+1056], b1v = lds[aw+1056+dz];
      acc  = fmaf(wz0*xv, w0v, fmaf(wz1*xv, w1v, acc));
      bacc = fmaf(wz0,    b0v, fmaf(wz1,    b1v, bacc));
    }
  }
  float vout = acc + bacc*(1.f/16.f);
  outp[((size_t)(b*COc+o)*Hc + hp)*Wc + wq] = vout;

  // deterministic stats: reduce over 4 px in wave, then 4 waves via LDS
  float sm = vout, sq = vout*vout;
  sm += __shfl_xor(sm,1); sq += __shfl_xor(sq,1);
  sm += __shfl_xor(sm,2); sq += __shfl_xor(sq,2);
  __syncthreads();
  if(pl==0){ lds[(wv*16+o)*2] = sm; lds[(wv*16+o)*2+1] = sq; }
  __syncthreads();
  if(tid < 32){
    int oo = tid>>1, kd = tid&1;
    float S = ((lds[(0*16+oo)*2+kd] + lds[(1*16+oo)*2+kd])
             + (lds[(2*16+oo)*2+kd] + lds[(3*16+oo)*2+kd]));
    int blk = (b*256 + hp)*16 + xseg;       // P=8192
    pacc[kd*131072 + oo*8192 + blk] = S;    // CP = 16*8192
  }
}

// ---- final BN + SiLU in place on d_out ----
__global__ void k_final(float* __restrict__ out, const float* __restrict__ A,
                        const float* __restrict__ B){
  int idx = blockIdx.x*256 + threadIdx.x;
  int c = (idx>>16)&15;
  float y = fmaf(out[idx], A[c], B[c]);
  out[idx] = y / (1.f + expf(-y));
}

} // namespace

extern "C" void kernel_launch(void* const* d_in, const int* in_sizes, int n_in,
                              void* d_out, int out_size, void* d_ws, size_t ws_size,
                              hipStream_t stream){
  const float* x       = (const float*)d_in[0];
  const float* conv0_w = (const float*)d_in[1];
  const float* conv0_b = (const float*)d_in[2];
  const float* prelu0  = (const float*)d_in[3];
  const float* c1w  = (const float*)d_in[4];
  const float* c1b  = (const float*)d_in[5];
  const float* bn1g = (const float*)d_in[6];
  const float* bn1b = (const float*)d_in[7];
  const float* p1   = (const float*)d_in[8];
  const float* dww  = (const float*)d_in[9];
  const float* dwb  = (const float*)d_in[10];
  const float* bn2g = (const float*)d_in[11];
  const float* bn2b = (const float*)d_in[12];
  const float* p2   = (const float*)d_in[13];
  const float* c3w  = (const float*)d_in[14];
  const float* c3b  = (const float*)d_in[15];
  const float* bn3g = (const float*)d_in[16];
  const float* bn3b = (const float*)d_in[17];
  const float* p3   = (const float*)d_in[18];
  const float* hw   = (const float*)d_in[19];
  const float* hb   = (const float*)d_in[20];
  const float* obg  = (const float*)d_in[21];
  const float* obb  = (const float*)d_in[22];
  float* out = (float*)d_out;
  float* ws  = (float*)d_ws;

  // workspace (floats)
  float* xd   = ws;                 // 131072
  float* h    = xd + 131072;        // 524288
  float* A    = h  + 524288;        // 320
  float* B    = A  + 320;           // 320
  float* pacc = B  + 320;           // 81920 (loop-phase partials)
  float* t1   = pacc + 81920;       // 2621440
  float* t2   = t1 + 2621440;       // 2621440
  float* ts   = t2 + 2621440;       // 524288
  float* gv   = t1;                 // 4194304 aliases t1+t2 (dead by head)
  float* pacc2= ts;                 // 262144 slice partials alias ts (dead after loop)

  k_down <<<512,  256, 0, stream>>>(x, xd);
  k_conv0<<<2048, 256, 0, stream>>>(xd, conv0_w, conv0_b, prelu0, h);

  for(int i=0; i<3; i++){
    k_c1  <<<dim3(8,64,Bn), 256, 0, stream>>>(h, c1w + i*20480, c1b + i*320, t1, pacc);
    k_fin <<<320, 256, 0, stream>>>(pacc, 128, 1.f/8192.f, bn1g+i*320, bn1b+i*320, A, B);
    k_dw_s<<<10240, 256, 0, stream>>>(t1, dww + i*2880, dwb + i*320, A, B, p1+i, t2, pacc);
    k_fin <<<320, 256, 0, stream>>>(pacc, 32, 1.f/8192.f, bn2g+i*320, bn2b+i*320, A, B);
    k_c3  <<<dim3(256,Bn), 256, 0, stream>>>(t2, c3w + i*20480, c3b + i*64, A, B, p2+i, ts, pacc);
    k_fin <<<64, 256, 0, stream>>>(pacc, 512, 1.f/8192.f, bn3g+i*64, bn3b+i*64, A, B);
    k_addres<<<2048, 256, 0, stream>>>(ts, h, A, B, p3+i);
  }

  k_head_t<<<512, 256, 0, stream>>>(h, hw, hb, gv);
  k_slice <<<dim3(16,256,Bn), 256, 0, stream>>>(x, gv, out, pacc2);
  k_fin   <<<16, 256, 0, stream>>>(pacc2, 8192, 1.f/131072.f, obg, obb, A, B);
  k_final <<<8192, 256, 0, stream>>>(out, A, B);
}

// Round 12
// 624.050 us; speedup vs baseline: 1.1073x; 1.1073x over previous
//
#include <hip/hip_runtime.h>
#include <math.h>

namespace {

constexpr int Bn=2, CIc=16, COc=16, Hc=256, Wc=256, HIDc=64, C5c=320;
constexpr int SPc = 4096;               // 64*64
constexpr float EPSc = 1e-5f;

// ---- 4x4 mean downsample: x (B,16,256,256) -> xd (B,16,64,64) ----
__global__ void k_down(const float* __restrict__ x, float* __restrict__ xd){
  int idx = blockIdx.x*blockDim.x + threadIdx.x;
  if (idx >= Bn*CIc*SPc) return;
  int q = idx & 63, p = (idx>>6)&63, c = idx>>12;
  const float* xp = x + ((size_t)c*Hc + p*4)*Wc + q*4;
  float s = 0.f;
  #pragma unroll
  for(int dy=0; dy<4; dy++)
    #pragma unroll
    for(int dx=0; dx<4; dx++) s += xp[dy*Wc+dx];
  xd[idx] = s * (1.f/16.f);
}

// ---- conv0 3x3 pad1 (16->64) + scalar PReLU ----
__global__ void k_conv0(const float* __restrict__ xd, const float* __restrict__ w,
                        const float* __restrict__ bias, const float* __restrict__ a0,
                        float* __restrict__ h){
  int idx = blockIdx.x*blockDim.x + threadIdx.x;
  if (idx >= Bn*HIDc*SPc) return;
  int q = idx&63, p=(idx>>6)&63, co=(idx>>12)&63, b=idx/(HIDc*SPc);
  float acc = bias[co];
  for(int ci=0; ci<CIc; ci++){
    const float* xp = xd + (size_t)(b*CIc+ci)*SPc;
    const float* wp = w + (co*CIc+ci)*9;
    #pragma unroll
    for(int u=0; u<3; u++){
      int pp = p+u-1; if((unsigned)pp >= 64u) continue;
      #pragma unroll
      for(int v=0; v<3; v++){
        int qq = q+v-1; if((unsigned)qq >= 64u) continue;
        acc = fmaf(xp[pp*64+qq], wp[u*3+v], acc);
      }
    }
  }
  float a = a0[0];
  h[idx] = acc >= 0.f ? acc : a*acc;
}

// ---- fused 1x1 conv 64->320 + stat partials ----
__global__ void k_c1(const float* __restrict__ h, const float* __restrict__ w,
                     const float* __restrict__ bias, float* __restrict__ t1,
                     float* __restrict__ pacc){
  __shared__ float lh[64*64];
  int og = blockIdx.x, sj = blockIdx.y, b = blockIdx.z;
  int tid = threadIdx.x;
  for(int it=0; it<4; ++it){
    int f4 = tid + it*256;               // c*16 + s4
    int c = f4>>4, s4 = f4&15;
    float4 v = *(const float4*)(h + (size_t)(b*64+c)*SPc + sj*64 + s4*4);
    *(float4*)(&lh[c*64 + s4*4]) = v;
  }
  __syncthreads();
  int osub = tid>>6, s = tid&63;
  int ob = og*40 + osub*10;
  float acc[10];
  #pragma unroll
  for(int j=0;j<10;j++) acc[j] = bias[ob+j];
  for(int c=0;c<64;c++){
    float hv = lh[c*64+s];
    #pragma unroll
    for(int j=0;j<10;j++) acc[j] = fmaf(hv, w[(ob+j)*64 + c], acc[j]);
  }
  #pragma unroll
  for(int j=0;j<10;j++){
    int o = ob+j;
    t1[(size_t)(b*320+o)*SPc + sj*64 + s] = acc[j];
    float sm = acc[j], sq = acc[j]*acc[j];
    #pragma unroll
    for(int d=1; d<64; d<<=1){ sm += __shfl_xor(sm,d); sq += __shfl_xor(sq,d); }
    if(s==0){
      pacc[o*128 + b*64 + sj]         = sm;   // P=128
      pacc[40960 + o*128 + b*64 + sj] = sq;   // CP = 320*128
    }
  }
}

// ---- finalize: partials -> fused BN scale/shift A,B (deterministic) ----
__global__ void k_fin(const float* __restrict__ pacc, int P, float invN,
                      const float* __restrict__ g, const float* __restrict__ bb,
                      float* __restrict__ A, float* __restrict__ B){
  __shared__ double sh[256], sh2[256];
  int c = blockIdx.x, C = gridDim.x, tid = threadIdx.x;
  double s=0.0, s2=0.0;
  for(int p=tid; p<P; p+=256){
    s  += (double)pacc[c*P+p];
    s2 += (double)pacc[C*P + c*P + p];
  }
  sh[tid]=s; sh2[tid]=s2; __syncthreads();
  for(int off=128; off>0; off>>=1){
    if(tid<off){ sh[tid]+=sh[tid+off]; sh2[tid]+=sh2[tid+off]; }
    __syncthreads();
  }
  if(tid==0){
    float m = (float)(sh[0]*(double)invN);
    float v = (float)(sh2[0]*(double)invN) - m*m;
    float r = rsqrtf(v + EPSc);
    float gc = g[c];
    A[c] = gc*r;
    B[c] = bb[c] - m*gc*r;
  }
}

// ---- depthwise 3x3 with BN1+PReLU1 on read + stat partials ----
__global__ void k_dw_s(const float* __restrict__ t1, const float* __restrict__ w,
                       const float* __restrict__ bias, const float* __restrict__ A,
                       const float* __restrict__ Bb, const float* __restrict__ ap,
                       float* __restrict__ t2, float* __restrict__ pacc){
  int idx = blockIdx.x*256 + threadIdx.x;
  int q = idx&63, p=(idx>>6)&63, c=(idx>>12)%C5c, b=idx/(C5c*SPc);
  float a1 = A[c], b1 = Bb[c], al = ap[0];
  const float* ip = t1 + (size_t)(b*C5c+c)*SPc;
  const float* wp = w + c*9;
  float acc = bias[c];
  #pragma unroll
  for(int u=0; u<3; u++){
    int pp = p+u-1; if((unsigned)pp >= 64u) continue;
    #pragma unroll
    for(int v=0; v<3; v++){
      int qq = q+v-1; if((unsigned)qq >= 64u) continue;
      float y = fmaf(ip[pp*64+qq], a1, b1);
      y = y >= 0.f ? y : al*y;
      acc = fmaf(y, wp[u*3+v], acc);
    }
  }
  t2[idx] = acc;
  float sm = acc, sq = acc*acc;
  #pragma unroll
  for(int d=1; d<64; d<<=1){ sm += __shfl_xor(sm,d); sq += __shfl_xor(sq,d); }
  __shared__ float sred[8];
  int wv = threadIdx.x>>6, ln = threadIdx.x&63;
  if(ln==0){ sred[wv]=sm; sred[4+wv]=sq; }
  __syncthreads();
  if(threadIdx.x==0){
    float S = ((sred[0]+sred[1])+(sred[2]+sred[3]));
    float Q = ((sred[4]+sred[5])+(sred[6]+sred[7]));
    int j = blockIdx.x & 15;
    pacc[c*32 + b*16 + j]         = S;   // P=32
    pacc[10240 + c*32 + b*16 + j] = Q;   // CP = 320*32
  }
}

// ---- fused 1x1 conv 320->64 with BN2+PReLU2 on read + stat partials ----
__global__ void k_c3(const float* __restrict__ t2, const float* __restrict__ w,
                     const float* __restrict__ bias, const float* __restrict__ A,
                     const float* __restrict__ Bb, const float* __restrict__ ap,
                     float* __restrict__ ts, float* __restrict__ pacc){
  __shared__ float li[80*16];     // 5 KB  [c80][s]
  __shared__ float lw[64*80];     // 20 KB [o][c80]
  int sjf = blockIdx.x, b = blockIdx.y, tid = threadIdx.x;
  float al = ap[0];
  int og = tid>>4, s = tid&15;
  float acc[4];
  #pragma unroll
  for(int j=0;j<4;j++) acc[j] = bias[og*4+j];

  for(int cc=0; cc<4; cc++){
    __syncthreads();
    {
      int t = tid;
      for(int r=0; r<2; ++r, t+=256){
        if(t < 320){
          int c = t>>2, k = t&3;
          int cg = cc*80 + c;
          float4 v = *(const float4*)(t2 + (size_t)(b*C5c+cg)*SPc + sjf*16 + k*4);
          float4 y;
          float a1 = A[cg], b1 = Bb[cg];
          y.x = fmaf(v.x, a1, b1); y.x = y.x>=0.f ? y.x : al*y.x;
          y.y = fmaf(v.y, a1, b1); y.y = y.y>=0.f ? y.y : al*y.y;
          y.z = fmaf(v.z, a1, b1); y.z = y.z>=0.f ? y.z : al*y.z;
          y.w = fmaf(v.w, a1, b1); y.w = y.w>=0.f ? y.w : al*y.w;
          *(float4*)(&li[c*16 + k*4]) = y;
        }
      }
    }
    for(int t = tid; t < 1280; t += 256){
      int o = t/20, k = t%20;
      float4 v = *(const float4*)(w + (size_t)o*C5c + cc*80 + k*4);
      *(float4*)(&lw[o*80 + k*4]) = v;
    }
    __syncthreads();
    for(int c=0; c<80; c++){
      float hv = li[c*16 + s];
      #pragma unroll
      for(int j=0;j<4;j++)
        acc[j] = fmaf(hv, lw[(og*4+j)*80 + c], acc[j]);
    }
  }

  #pragma unroll
  for(int j=0;j<4;j++){
    int o = og*4+j;
    ts[(size_t)(b*64+o)*SPc + sjf*16 + s] = acc[j];
    float sm = acc[j], sq = acc[j]*acc[j];
    #pragma unroll
    for(int d=1; d<16; d<<=1){ sm += __shfl_xor(sm,d); sq += __shfl_xor(sq,d); }
    if(s==0){
      pacc[o*512 + b*256 + sjf]         = sm;  // P=512
      pacc[32768 + o*512 + b*256 + sjf] = sq;  // CP = 64*512
    }
  }
}

// ---- BN3 + PReLU3 + residual add into h ----
__global__ void k_addres(const float* __restrict__ ts, float* __restrict__ h,
                         const float* __restrict__ A, const float* __restrict__ Bb,
                         const float* __restrict__ ap){
  int idx = blockIdx.x*256 + threadIdx.x;
  int c = (idx>>12)&63;
  float y = fmaf(ts[idx], A[c], Bb[c]);
  float al = ap[0];
  y = y >= 0.f ? y : al*y;
  h[idx] += y;
}

// ---- head 1x1 conv (64->512) writing z-innermost gvol, chunk=[k2][o16][z64] ----
// gv: [b][y=q(64)][x=ci(16)][k(2)][o(16)][z=p(64)]
__global__ void k_head_t(const float* __restrict__ h, const float* __restrict__ w,
                         const float* __restrict__ bias, float* __restrict__ gv){
  __shared__ float sb0[64*65], sb1[64*65];
  int bid = blockIdx.x;            // (b*16 + o)*16 + ci
  int ci = bid & 15, o = (bid>>4) & 15, b = bid >> 8;
  int c0 = (o*16 + ci)*2, c1 = c0 + 1;
  const float* hp0 = h + (size_t)b*HIDc*SPc;
  const float* w0 = w + (size_t)c0*HIDc;
  const float* w1 = w + (size_t)c1*HIDc;
  float b0 = bias[c0], b1 = bias[c1];
  int tid = threadIdx.x;
  for(int j=0; j<16; j++){
    int s = tid + j*256;           // s = p*64 + q
    float a0 = b0, a1 = b1;
    #pragma unroll 8
    for(int kc=0; kc<HIDc; kc++){
      float hv = hp0[kc*SPc + s];
      a0 = fmaf(hv, w0[kc], a0);
      a1 = fmaf(hv, w1[kc], a1);
    }
    int pad = s + (s>>6);
    sb0[pad] = a0; sb1[pad] = a1;
  }
  __syncthreads();
  float* gb = gv + (size_t)b*(64*16*2048);
  for(int j=0; j<16; j++){
    int t = tid + j*256;
    int q = t>>6, p = t&63;
    size_t base = ((size_t)(q*16 + ci))*2048 + (size_t)o*64 + p;
    gb[base]        = sb0[p*65 + q];   // k=0 weight plane
    gb[base + 1024] = sb1[p*65 + q];   // k=1 bias plane
  }
}

// ---- slice v3: 1 row x 16 cols/block; y-blend at staging (6->2 corners);
// pair-duplicated z so the 2 z-taps are ONE ds_read_b64.
// LDS: 3 merged x-chunks x [k2][o16][65 float2] = 6240 float2 = 49.9 KB
__global__ void k_slice(const float* __restrict__ x, const float* __restrict__ gv,
                        float* __restrict__ outp, float* __restrict__ pacc){
  __shared__ float lds[12480];
  int xseg = blockIdx.x, hp = blockIdx.y, b = blockIdx.z;
  int tid = threadIdx.x;
  const float* gb = gv + (size_t)b*(64*16*2048);
  int y0 = (hp*63)/255;
  int y1 = min(y0+1, 63);
  float fy = hp*(63.f/255.f) - (float)y0;
  int xbase = (xseg*240)/255;

  // stage + y-blend: 96 threads, each owns one (chunk, k, o) z-line
  if(tid < 96){
    int cix = tid >> 5, r = tid & 31;
    int k = r >> 4, o = r & 15;
    int xs = min(xbase + cix, 15);
    const float4* s0 = (const float4*)(gb + (size_t)(y0*16+xs)*2048 + k*1024 + o*64);
    const float4* s1 = (const float4*)(gb + (size_t)(y1*16+xs)*2048 + k*1024 + o*64);
    float2* d = (float2*)lds + cix*2080 + k*1040 + o*65;
    float prev = 0.f;
    #pragma unroll
    for(int j=0; j<16; ++j){
      float4 a = s0[j], c = s1[j];
      float b0 = fmaf(fy, c.x-a.x, a.x);
      float b1 = fmaf(fy, c.y-a.y, a.y);
      float b2 = fmaf(fy, c.z-a.z, a.z);
      float b3 = fmaf(fy, c.w-a.w, a.w);
      if(j) d[4*j-1] = make_float2(prev, b0);
      d[4*j]   = make_float2(b0, b1);
      d[4*j+1] = make_float2(b1, b2);
      d[4*j+2] = make_float2(b2, b3);
      prev = b3;
    }
    d[63] = make_float2(prev, prev);
  }
  __syncthreads();

  int wv = tid>>6, lane = tid&63;
  int o = lane>>2, pl = lane&3;
  int lc = wv*4 + pl;
  int wq = xseg*16 + lc;

  int x0 = (wq*15)/255;
  float fx = wq*(15.f/255.f) - (float)x0;
  int x1 = min(x0+1, 15);
  int cA = (x0 - xbase)*2080, cB = (x1 - xbase)*2080;
  float cwA = 1.f-fx, cwB = fx;
  int obase = o*65;
  const float2* l2 = (const float2*)lds;

  float acc = 0.f, bacc = 0.f;
  for(int i=0; i<CIc; i++){
    float xv = x[((size_t)(b*CIc+i)*Hc + hp)*Wc + wq];
    float g = fminf(fmaxf(xv, 0.f), 1.f);
    float pz = g*63.f;
    int z0 = (int)pz; float fz = pz - (float)z0;
    float wz0 = cwA*(1.f-fz), wz1 = cwA*fz;
    float vz0 = cwB*(1.f-fz), vz1 = cwB*fz;
    int aA = cA + obase + z0, aB = cB + obase + z0;
    float2 wA = l2[aA],        wB = l2[aB];
    float2 bA = l2[aA + 1040], bB = l2[aB + 1040];
    float wsum = fmaf(wz0, wA.x, fmaf(wz1, wA.y, fmaf(vz0, wB.x, vz1*wB.y)));
    float bsum = fmaf(wz0, bA.x, fmaf(wz1, bA.y, fmaf(vz0, bB.x, vz1*bB.y)));
    acc  = fmaf(xv, wsum, acc);
    bacc += bsum;
  }
  float vout = acc + bacc*(1.f/16.f);
  outp[((size_t)(b*COc+o)*Hc + hp)*Wc + wq] = vout;

  // deterministic stats: 4 px in wave, then 4 waves via LDS
  float sm = vout, sq = vout*vout;
  sm += __shfl_xor(sm,1); sq += __shfl_xor(sq,1);
  sm += __shfl_xor(sm,2); sq += __shfl_xor(sq,2);
  __syncthreads();
  if(pl==0){ lds[(wv*16+o)*2] = sm; lds[(wv*16+o)*2+1] = sq; }
  __syncthreads();
  if(tid < 32){
    int oo = tid>>1, kd = tid&1;
    float S = ((lds[(0*16+oo)*2+kd] + lds[(1*16+oo)*2+kd])
             + (lds[(2*16+oo)*2+kd] + lds[(3*16+oo)*2+kd]));
    int blk = (b*256 + hp)*16 + xseg;       // P=8192
    pacc[kd*131072 + oo*8192 + blk] = S;    // CP = 16*8192
  }
}

// ---- final BN + SiLU in place on d_out ----
__global__ void k_final(float* __restrict__ out, const float* __restrict__ A,
                        const float* __restrict__ B){
  int idx = blockIdx.x*256 + threadIdx.x;
  int c = (idx>>16)&15;
  float y = fmaf(out[idx], A[c], B[c]);
  out[idx] = y / (1.f + expf(-y));
}

} // namespace

extern "C" void kernel_launch(void* const* d_in, const int* in_sizes, int n_in,
                              void* d_out, int out_size, void* d_ws, size_t ws_size,
                              hipStream_t stream){
  const float* x       = (const float*)d_in[0];
  const float* conv0_w = (const float*)d_in[1];
  const float* conv0_b = (const float*)d_in[2];
  const float* prelu0  = (const float*)d_in[3];
  const float* c1w  = (const float*)d_in[4];
  const float* c1b  = (const float*)d_in[5];
  const float* bn1g = (const float*)d_in[6];
  const float* bn1b = (const float*)d_in[7];
  const float* p1   = (const float*)d_in[8];
  const float* dww  = (const float*)d_in[9];
  const float* dwb  = (const float*)d_in[10];
  const float* bn2g = (const float*)d_in[11];
  const float* bn2b = (const float*)d_in[12];
  const float* p2   = (const float*)d_in[13];
  const float* c3w  = (const float*)d_in[14];
  const float* c3b  = (const float*)d_in[15];
  const float* bn3g = (const float*)d_in[16];
  const float* bn3b = (const float*)d_in[17];
  const float* p3   = (const float*)d_in[18];
  const float* hw   = (const float*)d_in[19];
  const float* hb   = (const float*)d_in[20];
  const float* obg  = (const float*)d_in[21];
  const float* obb  = (const float*)d_in[22];
  float* out = (float*)d_out;
  float* ws  = (float*)d_ws;

  // workspace (floats)
  float* xd   = ws;                 // 131072
  float* h    = xd + 131072;        // 524288
  float* A    = h  + 524288;        // 320
  float* B    = A  + 320;           // 320
  float* pacc = B  + 320;           // 81920 (loop-phase partials)
  float* t1   = pacc + 81920;       // 2621440
  float* t2   = t1 + 2621440;       // 2621440
  float* ts   = t2 + 2621440;       // 524288
  float* gv   = t1;                 // 4194304 aliases t1+t2 (dead by head)
  float* pacc2= ts;                 // 262144 slice partials alias ts (dead after loop)

  k_down <<<512,  256, 0, stream>>>(x, xd);
  k_conv0<<<2048, 256, 0, stream>>>(xd, conv0_w, conv0_b, prelu0, h);

  for(int i=0; i<3; i++){
    k_c1  <<<dim3(8,64,Bn), 256, 0, stream>>>(h, c1w + i*20480, c1b + i*320, t1, pacc);
    k_fin <<<320, 256, 0, stream>>>(pacc, 128, 1.f/8192.f, bn1g+i*320, bn1b+i*320, A, B);
    k_dw_s<<<10240, 256, 0, stream>>>(t1, dww + i*2880, dwb + i*320, A, B, p1+i, t2, pacc);
    k_fin <<<320, 256, 0, stream>>>(pacc, 32, 1.f/8192.f, bn2g+i*320, bn2b+i*320, A, B);
    k_c3  <<<dim3(256,Bn), 256, 0, stream>>>(t2, c3w + i*20480, c3b + i*64, A, B, p2+i, ts, pacc);
    k_fin <<<64, 256, 0, stream>>>(pacc, 512, 1.f/8192.f, bn3g+i*64, bn3b+i*64, A, B);
    k_addres<<<2048, 256, 0, stream>>>(ts, h, A, B, p3+i);
  }

  k_head_t<<<512, 256, 0, stream>>>(h, hw, hb, gv);
  k_slice <<<dim3(16,256,Bn), 256, 0, stream>>>(x, gv, out, pacc2);
  k_fin   <<<16, 256, 0, stream>>>(pacc2, 8192, 1.f/131072.f, obg, obb, A, B);
  k_final <<<8192, 256, 0, stream>>>(out, A, B);
}

// Round 13
// 532.698 us; speedup vs baseline: 1.2972x; 1.1715x over previous
//
#include <hip/hip_runtime.h>
#include <math.h>

namespace {

constexpr int Bn=2, CIc=16, COc=16, Hc=256, Wc=256, HIDc=64, C5c=320;
constexpr int SPc = 4096;               // 64*64
constexpr float EPSc = 1e-5f;

// ---- 4x4 mean downsample: x (B,16,256,256) -> xd (B,16,64,64) ----
__global__ void k_down(const float* __restrict__ x, float* __restrict__ xd){
  int idx = blockIdx.x*blockDim.x + threadIdx.x;
  if (idx >= Bn*CIc*SPc) return;
  int q = idx & 63, p = (idx>>6)&63, c = idx>>12;
  const float* xp = x + ((size_t)c*Hc + p*4)*Wc + q*4;
  float s = 0.f;
  #pragma unroll
  for(int dy=0; dy<4; dy++)
    #pragma unroll
    for(int dx=0; dx<4; dx++) s += xp[dy*Wc+dx];
  xd[idx] = s * (1.f/16.f);
}

// ---- conv0 3x3 pad1 (16->64) + scalar PReLU ----
__global__ void k_conv0(const float* __restrict__ xd, const float* __restrict__ w,
                        const float* __restrict__ bias, const float* __restrict__ a0,
                        float* __restrict__ h){
  int idx = blockIdx.x*blockDim.x + threadIdx.x;
  if (idx >= Bn*HIDc*SPc) return;
  int q = idx&63, p=(idx>>6)&63, co=(idx>>12)&63, b=idx/(HIDc*SPc);
  float acc = bias[co];
  for(int ci=0; ci<CIc; ci++){
    const float* xp = xd + (size_t)(b*CIc+ci)*SPc;
    const float* wp = w + (co*CIc+ci)*9;
    #pragma unroll
    for(int u=0; u<3; u++){
      int pp = p+u-1; if((unsigned)pp >= 64u) continue;
      #pragma unroll
      for(int v=0; v<3; v++){
        int qq = q+v-1; if((unsigned)qq >= 64u) continue;
        acc = fmaf(xp[pp*64+qq], wp[u*3+v], acc);
      }
    }
  }
  float a = a0[0];
  h[idx] = acc >= 0.f ? acc : a*acc;
}

// ---- fused 1x1 conv 64->320 + stat partials ----
__global__ void k_c1(const float* __restrict__ h, const float* __restrict__ w,
                     const float* __restrict__ bias, float* __restrict__ t1,
                     float* __restrict__ pacc){
  __shared__ float lh[64*64];
  int og = blockIdx.x, sj = blockIdx.y, b = blockIdx.z;
  int tid = threadIdx.x;
  for(int it=0; it<4; ++it){
    int f4 = tid + it*256;               // c*16 + s4
    int c = f4>>4, s4 = f4&15;
    float4 v = *(const float4*)(h + (size_t)(b*64+c)*SPc + sj*64 + s4*4);
    *(float4*)(&lh[c*64 + s4*4]) = v;
  }
  __syncthreads();
  int osub = tid>>6, s = tid&63;
  int ob = og*40 + osub*10;
  float acc[10];
  #pragma unroll
  for(int j=0;j<10;j++) acc[j] = bias[ob+j];
  for(int c=0;c<64;c++){
    float hv = lh[c*64+s];
    #pragma unroll
    for(int j=0;j<10;j++) acc[j] = fmaf(hv, w[(ob+j)*64 + c], acc[j]);
  }
  #pragma unroll
  for(int j=0;j<10;j++){
    int o = ob+j;
    t1[(size_t)(b*320+o)*SPc + sj*64 + s] = acc[j];
    float sm = acc[j], sq = acc[j]*acc[j];
    #pragma unroll
    for(int d=1; d<64; d<<=1){ sm += __shfl_xor(sm,d); sq += __shfl_xor(sq,d); }
    if(s==0){
      pacc[o*128 + b*64 + sj]         = sm;   // P=128
      pacc[40960 + o*128 + b*64 + sj] = sq;   // CP = 320*128
    }
  }
}

// ---- finalize: partials -> fused BN scale/shift A,B (deterministic) ----
__global__ void k_fin(const float* __restrict__ pacc, int P, float invN,
                      const float* __restrict__ g, const float* __restrict__ bb,
                      float* __restrict__ A, float* __restrict__ B){
  __shared__ double sh[256], sh2[256];
  int c = blockIdx.x, C = gridDim.x, tid = threadIdx.x;
  double s=0.0, s2=0.0;
  for(int p=tid; p<P; p+=256){
    s  += (double)pacc[c*P+p];
    s2 += (double)pacc[C*P + c*P + p];
  }
  sh[tid]=s; sh2[tid]=s2; __syncthreads();
  for(int off=128; off>0; off>>=1){
    if(tid<off){ sh[tid]+=sh[tid+off]; sh2[tid]+=sh2[tid+off]; }
    __syncthreads();
  }
  if(tid==0){
    float m = (float)(sh[0]*(double)invN);
    float v = (float)(sh2[0]*(double)invN) - m*m;
    float r = rsqrtf(v + EPSc);
    float gc = g[c];
    A[c] = gc*r;
    B[c] = bb[c] - m*gc*r;
  }
}

// ---- depthwise 3x3 with BN1+PReLU1 on read + stat partials ----
__global__ void k_dw_s(const float* __restrict__ t1, const float* __restrict__ w,
                       const float* __restrict__ bias, const float* __restrict__ A,
                       const float* __restrict__ Bb, const float* __restrict__ ap,
                       float* __restrict__ t2, float* __restrict__ pacc){
  int idx = blockIdx.x*256 + threadIdx.x;
  int q = idx&63, p=(idx>>6)&63, c=(idx>>12)%C5c, b=idx/(C5c*SPc);
  float a1 = A[c], b1 = Bb[c], al = ap[0];
  const float* ip = t1 + (size_t)(b*C5c+c)*SPc;
  const float* wp = w + c*9;
  float acc = bias[c];
  #pragma unroll
  for(int u=0; u<3; u++){
    int pp = p+u-1; if((unsigned)pp >= 64u) continue;
    #pragma unroll
    for(int v=0; v<3; v++){
      int qq = q+v-1; if((unsigned)qq >= 64u) continue;
      float y = fmaf(ip[pp*64+qq], a1, b1);
      y = y >= 0.f ? y : al*y;
      acc = fmaf(y, wp[u*3+v], acc);
    }
  }
  t2[idx] = acc;
  float sm = acc, sq = acc*acc;
  #pragma unroll
  for(int d=1; d<64; d<<=1){ sm += __shfl_xor(sm,d); sq += __shfl_xor(sq,d); }
  __shared__ float sred[8];
  int wv = threadIdx.x>>6, ln = threadIdx.x&63;
  if(ln==0){ sred[wv]=sm; sred[4+wv]=sq; }
  __syncthreads();
  if(threadIdx.x==0){
    float S = ((sred[0]+sred[1])+(sred[2]+sred[3]));
    float Q = ((sred[4]+sred[5])+(sred[6]+sred[7]));
    int j = blockIdx.x & 15;
    pacc[c*32 + b*16 + j]         = S;   // P=32
    pacc[10240 + c*32 + b*16 + j] = Q;   // CP = 320*32
  }
}

// ---- split-K partial 1x1 conv 320->64 with BN2+PReLU2 on read ----
// grid (64 sj, 4 kk, Bn), 256 thr. Block: 64 px, 80 in-ch quarter.
// Input staged in LDS (256-B coalesced); weights via wave-uniform broadcast
// (R8-verified clean cache path). Partials (no bias) -> tsp slab kk.
__global__ void k_c3p(const float* __restrict__ t2, const float* __restrict__ w,
                      const float* __restrict__ A, const float* __restrict__ Bb,
                      const float* __restrict__ ap, float* __restrict__ tsp){
  __shared__ float li[80*64];     // 20 KB
  int sj = blockIdx.x, kk = blockIdx.y, b = blockIdx.z;
  int tid = threadIdx.x;
  float al = ap[0];
  for(int t = tid; t < 1280; t += 256){
    int c = t>>4, k4 = t&15;
    int cg = kk*80 + c;
    float4 v = *(const float4*)(t2 + (size_t)(b*C5c+cg)*SPc + sj*64 + k4*4);
    float a1 = A[cg], b1 = Bb[cg];
    float4 y;
    y.x = fmaf(v.x, a1, b1); y.x = y.x>=0.f ? y.x : al*y.x;
    y.y = fmaf(v.y, a1, b1); y.y = y.y>=0.f ? y.y : al*y.y;
    y.z = fmaf(v.z, a1, b1); y.z = y.z>=0.f ? y.z : al*y.z;
    y.w = fmaf(v.w, a1, b1); y.w = y.w>=0.f ? y.w : al*y.w;
    *(float4*)(&li[c*64 + k4*4]) = y;
  }
  __syncthreads();
  int og = tid>>6, s = tid&63;     // og wave-uniform
  float acc[16];
  #pragma unroll
  for(int j=0;j<16;j++) acc[j] = 0.f;
  const float* wb = w + (size_t)(og*16)*C5c + kk*80;
  for(int c=0; c<80; c++){
    float hv = li[c*64 + s];
    #pragma unroll
    for(int j=0;j<16;j++)
      acc[j] = fmaf(hv, wb[j*C5c + c], acc[j]);
  }
  float* dst = tsp + (size_t)kk*524288 + (size_t)(b*64 + og*16)*SPc + sj*64 + s;
  #pragma unroll
  for(int j=0;j<16;j++) dst[(size_t)j*SPc] = acc[j];
}

// ---- sum 4 split-K slabs + bias -> ts, emit BN3 stat partials ----
// grid 2048, 256 thr; each block covers one 256-px chunk of one (b,o) row
__global__ void k_sum(const float* __restrict__ tsp, const float* __restrict__ bias,
                      float* __restrict__ ts, float* __restrict__ pacc){
  int idx = blockIdx.x*256 + threadIdx.x;
  int o = (idx>>12)&63, b = idx>>18;
  float v = bias[o];
  v += tsp[idx];
  v += tsp[524288 + idx];
  v += tsp[1048576 + idx];
  v += tsp[1572864 + idx];
  ts[idx] = v;
  float sm = v, sq = v*v;
  #pragma unroll
  for(int d=1; d<64; d<<=1){ sm += __shfl_xor(sm,d); sq += __shfl_xor(sq,d); }
  __shared__ float sred[8];
  int wv = threadIdx.x>>6, ln = threadIdx.x&63;
  if(ln==0){ sred[wv]=sm; sred[4+wv]=sq; }
  __syncthreads();
  if(threadIdx.x==0){
    float S = ((sred[0]+sred[1])+(sred[2]+sred[3]));
    float Q = ((sred[4]+sred[5])+(sred[6]+sred[7]));
    int j = blockIdx.x & 15;
    pacc[o*32 + b*16 + j]        = S;   // P=32
    pacc[2048 + o*32 + b*16 + j] = Q;   // CP = 64*32
  }
}

// ---- BN3 + PReLU3 + residual add into h ----
__global__ void k_addres(const float* __restrict__ ts, float* __restrict__ h,
                         const float* __restrict__ A, const float* __restrict__ Bb,
                         const float* __restrict__ ap){
  int idx = blockIdx.x*256 + threadIdx.x;
  int c = (idx>>12)&63;
  float y = fmaf(ts[idx], A[c], Bb[c]);
  float al = ap[0];
  y = y >= 0.f ? y : al*y;
  h[idx] += y;
}

// ---- head 1x1 conv (64->512) writing z-innermost gvol, chunk=[k2][o16][z64] ----
// gv: [b][y=q(64)][x=ci(16)][k(2)][o(16)][z=p(64)]
__global__ void k_head_t(const float* __restrict__ h, const float* __restrict__ w,
                         const float* __restrict__ bias, float* __restrict__ gv){
  __shared__ float sb0[64*65], sb1[64*65];
  int bid = blockIdx.x;            // (b*16 + o)*16 + ci
  int ci = bid & 15, o = (bid>>4) & 15, b = bid >> 8;
  int c0 = (o*16 + ci)*2, c1 = c0 + 1;
  const float* hp0 = h + (size_t)b*HIDc*SPc;
  const float* w0 = w + (size_t)c0*HIDc;
  const float* w1 = w + (size_t)c1*HIDc;
  float b0 = bias[c0], b1 = bias[c1];
  int tid = threadIdx.x;
  for(int j=0; j<16; j++){
    int s = tid + j*256;           // s = p*64 + q
    float a0 = b0, a1 = b1;
    #pragma unroll 8
    for(int kc=0; kc<HIDc; kc++){
      float hv = hp0[kc*SPc + s];
      a0 = fmaf(hv, w0[kc], a0);
      a1 = fmaf(hv, w1[kc], a1);
    }
    int pad = s + (s>>6);
    sb0[pad] = a0; sb1[pad] = a1;
  }
  __syncthreads();
  float* gb = gv + (size_t)b*(64*16*2048);
  for(int j=0; j<16; j++){
    int t = tid + j*256;
    int q = t>>6, p = t&63;
    size_t base = ((size_t)(q*16 + ci))*2048 + (size_t)o*64 + p;
    gb[base]        = sb0[p*65 + q];   // k=0 weight plane
    gb[base + 1024] = sb1[p*65 + q];   // k=1 bias plane
  }
}

// ---- slice v3: 1 row x 16 cols/block; y-blend at staging (6->2 corners);
// pair-duplicated z so the 2 z-taps are ONE ds_read_b64.
// LDS: 3 merged x-chunks x [k2][o16][65 float2] = 6240 float2 = 49.9 KB
__global__ void k_slice(const float* __restrict__ x, const float* __restrict__ gv,
                        float* __restrict__ outp, float* __restrict__ pacc){
  __shared__ float lds[12480];
  int xseg = blockIdx.x, hp = blockIdx.y, b = blockIdx.z;
  int tid = threadIdx.x;
  const float* gb = gv + (size_t)b*(64*16*2048);
  int y0 = (hp*63)/255;
  int y1 = min(y0+1, 63);
  float fy = hp*(63.f/255.f) - (float)y0;
  int xbase = (xseg*240)/255;

  // stage + y-blend: 96 threads, each owns one (chunk, k, o) z-line
  if(tid < 96){
    int cix = tid >> 5, r = tid & 31;
    int k = r >> 4, o = r & 15;
    int xs = min(xbase + cix, 15);
    const float4* s0 = (const float4*)(gb + (size_t)(y0*16+xs)*2048 + k*1024 + o*64);
    const float4* s1 = (const float4*)(gb + (size_t)(y1*16+xs)*2048 + k*1024 + o*64);
    float2* d = (float2*)lds + cix*2080 + k*1040 + o*65;
    float prev = 0.f;
    #pragma unroll
    for(int j=0; j<16; ++j){
      float4 a = s0[j], c = s1[j];
      float b0 = fmaf(fy, c.x-a.x, a.x);
      float b1 = fmaf(fy, c.y-a.y, a.y);
      float b2 = fmaf(fy, c.z-a.z, a.z);
      float b3 = fmaf(fy, c.w-a.w, a.w);
      if(j) d[4*j-1] = make_float2(prev, b0);
      d[4*j]   = make_float2(b0, b1);
      d[4*j+1] = make_float2(b1, b2);
      d[4*j+2] = make_float2(b2, b3);
      prev = b3;
    }
    d[63] = make_float2(prev, prev);
  }
  __syncthreads();

  int wv = tid>>6, lane = tid&63;
  int o = lane>>2, pl = lane&3;
  int lc = wv*4 + pl;
  int wq = xseg*16 + lc;

  int x0 = (wq*15)/255;
  float fx = wq*(15.f/255.f) - (float)x0;
  int x1 = min(x0+1, 15);
  int cA = (x0 - xbase)*2080, cB = (x1 - xbase)*2080;
  float cwA = 1.f-fx, cwB = fx;
  int obase = o*65;
  const float2* l2 = (const float2*)lds;

  float acc = 0.f, bacc = 0.f;
  for(int i=0; i<CIc; i++){
    float xv = x[((size_t)(b*CIc+i)*Hc + hp)*Wc + wq];
    float g = fminf(fmaxf(xv, 0.f), 1.f);
    float pz = g*63.f;
    int z0 = (int)pz; float fz = pz - (float)z0;
    float wz0 = cwA*(1.f-fz), wz1 = cwA*fz;
    float vz0 = cwB*(1.f-fz), vz1 = cwB*fz;
    int aA = cA + obase + z0, aB = cB + obase + z0;
    float2 wA = l2[aA],        wB = l2[aB];
    float2 bA = l2[aA + 1040], bB = l2[aB + 1040];
    float wsum = fmaf(wz0, wA.x, fmaf(wz1, wA.y, fmaf(vz0, wB.x, vz1*wB.y)));
    float bsum = fmaf(wz0, bA.x, fmaf(wz1, bA.y, fmaf(vz0, bB.x, vz1*bB.y)));
    acc  = fmaf(xv, wsum, acc);
    bacc += bsum;
  }
  float vout = acc + bacc*(1.f/16.f);
  outp[((size_t)(b*COc+o)*Hc + hp)*Wc + wq] = vout;

  // deterministic stats: 4 px in wave, then 4 waves via LDS
  float sm = vout, sq = vout*vout;
  sm += __shfl_xor(sm,1); sq += __shfl_xor(sq,1);
  sm += __shfl_xor(sm,2); sq += __shfl_xor(sq,2);
  __syncthreads();
  if(pl==0){ lds[(wv*16+o)*2] = sm; lds[(wv*16+o)*2+1] = sq; }
  __syncthreads();
  if(tid < 32){
    int oo = tid>>1, kd = tid&1;
    float S = ((lds[(0*16+oo)*2+kd] + lds[(1*16+oo)*2+kd])
             + (lds[(2*16+oo)*2+kd] + lds[(3*16+oo)*2+kd]));
    int blk = (b*256 + hp)*16 + xseg;       // P=8192
    pacc[kd*131072 + oo*8192 + blk] = S;    // CP = 16*8192
  }
}

// ---- final BN + SiLU in place on d_out ----
__global__ void k_final(float* __restrict__ out, const float* __restrict__ A,
                        const float* __restrict__ B){
  int idx = blockIdx.x*256 + threadIdx.x;
  int c = (idx>>16)&15;
  float y = fmaf(out[idx], A[c], B[c]);
  out[idx] = y / (1.f + expf(-y));
}

} // namespace

extern "C" void kernel_launch(void* const* d_in, const int* in_sizes, int n_in,
                              void* d_out, int out_size, void* d_ws, size_t ws_size,
                              hipStream_t stream){
  const float* x       = (const float*)d_in[0];
  const float* conv0_w = (const float*)d_in[1];
  const float* conv0_b = (const float*)d_in[2];
  const float* prelu0  = (const float*)d_in[3];
  const float* c1w  = (const float*)d_in[4];
  const float* c1b  = (const float*)d_in[5];
  const float* bn1g = (const float*)d_in[6];
  const float* bn1b = (const float*)d_in[7];
  const float* p1   = (const float*)d_in[8];
  const float* dww  = (const float*)d_in[9];
  const float* dwb  = (const float*)d_in[10];
  const float* bn2g = (const float*)d_in[11];
  const float* bn2b = (const float*)d_in[12];
  const float* p2   = (const float*)d_in[13];
  const float* c3w  = (const float*)d_in[14];
  const float* c3b  = (const float*)d_in[15];
  const float* bn3g = (const float*)d_in[16];
  const float* bn3b = (const float*)d_in[17];
  const float* p3   = (const float*)d_in[18];
  const float* hw   = (const float*)d_in[19];
  const float* hb   = (const float*)d_in[20];
  const float* obg  = (const float*)d_in[21];
  const float* obb  = (const float*)d_in[22];
  float* out = (float*)d_out;
  float* ws  = (float*)d_ws;

  // workspace (floats)
  float* xd   = ws;                 // 131072
  float* h    = xd + 131072;        // 524288
  float* A    = h  + 524288;        // 320
  float* B    = A  + 320;           // 320
  float* pacc = B  + 320;           // 81920 (loop-phase partials)
  float* t1   = pacc + 81920;       // 2621440
  float* t2   = t1 + 2621440;       // 2621440
  float* ts   = t2 + 2621440;       // 524288
  float* gv   = t1;                 // 4194304 aliases t1+t2 (dead by head)
  float* tsp  = t1;                 // 2097152 split-K slabs alias t1 (dead after k_dw_s)
  float* pacc2= ts;                 // 262144 slice partials alias ts (dead after loop)

  k_down <<<512,  256, 0, stream>>>(x, xd);
  k_conv0<<<2048, 256, 0, stream>>>(xd, conv0_w, conv0_b, prelu0, h);

  for(int i=0; i<3; i++){
    k_c1  <<<dim3(8,64,Bn), 256, 0, stream>>>(h, c1w + i*20480, c1b + i*320, t1, pacc);
    k_fin <<<320, 256, 0, stream>>>(pacc, 128, 1.f/8192.f, bn1g+i*320, bn1b+i*320, A, B);
    k_dw_s<<<10240, 256, 0, stream>>>(t1, dww + i*2880, dwb + i*320, A, B, p1+i, t2, pacc);
    k_fin <<<320, 256, 0, stream>>>(pacc, 32, 1.f/8192.f, bn2g+i*320, bn2b+i*320, A, B);
    k_c3p <<<dim3(64,4,Bn), 256, 0, stream>>>(t2, c3w + i*20480, A, B, p2+i, tsp);
    k_sum <<<2048, 256, 0, stream>>>(tsp, c3b + i*64, ts, pacc);
    k_fin <<<64, 256, 0, stream>>>(pacc, 32, 1.f/8192.f, bn3g+i*64, bn3b+i*64, A, B);
    k_addres<<<2048, 256, 0, stream>>>(ts, h, A, B, p3+i);
  }

  k_head_t<<<512, 256, 0, stream>>>(h, hw, hb, gv);
  k_slice <<<dim3(16,256,Bn), 256, 0, stream>>>(x, gv, out, pacc2);
  k_fin   <<<16, 256, 0, stream>>>(pacc2, 8192, 1.f/131072.f, obg, obb, A, B);
  k_final <<<8192, 256, 0, stream>>>(out, A, B);
}

// Round 14
// 520.327 us; speedup vs baseline: 1.3280x; 1.0238x over previous
//
#include <hip/hip_runtime.h>
#include <math.h>

namespace {

constexpr int Bn=2, CIc=16, COc=16, Hc=256, Wc=256, HIDc=64, C5c=320;
constexpr int SPc = 4096;               // 64*64
constexpr float EPSc = 1e-5f;

// ---- 4x4 mean downsample: x (B,16,256,256) -> xd (B,16,64,64) ----
__global__ void k_down(const float* __restrict__ x, float* __restrict__ xd){
  int idx = blockIdx.x*blockDim.x + threadIdx.x;
  if (idx >= Bn*CIc*SPc) return;
  int q = idx & 63, p = (idx>>6)&63, c = idx>>12;
  const float* xp = x + ((size_t)c*Hc + p*4)*Wc + q*4;
  float s = 0.f;
  #pragma unroll
  for(int dy=0; dy<4; dy++)
    #pragma unroll
    for(int dx=0; dx<4; dx++) s += xp[dy*Wc+dx];
  xd[idx] = s * (1.f/16.f);
}

// ---- conv0 3x3 pad1 (16->64) + scalar PReLU ----
__global__ void k_conv0(const float* __restrict__ xd, const float* __restrict__ w,
                        const float* __restrict__ bias, const float* __restrict__ a0,
                        float* __restrict__ h){
  int idx = blockIdx.x*blockDim.x + threadIdx.x;
  if (idx >= Bn*HIDc*SPc) return;
  int q = idx&63, p=(idx>>6)&63, co=(idx>>12)&63, b=idx/(HIDc*SPc);
  float acc = bias[co];
  for(int ci=0; ci<CIc; ci++){
    const float* xp = xd + (size_t)(b*CIc+ci)*SPc;
    const float* wp = w + (co*CIc+ci)*9;
    #pragma unroll
    for(int u=0; u<3; u++){
      int pp = p+u-1; if((unsigned)pp >= 64u) continue;
      #pragma unroll
      for(int v=0; v<3; v++){
        int qq = q+v-1; if((unsigned)qq >= 64u) continue;
        acc = fmaf(xp[pp*64+qq], wp[u*3+v], acc);
      }
    }
  }
  float a = a0[0];
  h[idx] = acc >= 0.f ? acc : a*acc;
}

// ---- fused 1x1 conv 64->320 + BN1 stat partials ----
__global__ void k_c1(const float* __restrict__ h, const float* __restrict__ w,
                     const float* __restrict__ bias, float* __restrict__ t1,
                     float* __restrict__ pacc){
  __shared__ float lh[64*64];
  int og = blockIdx.x, sj = blockIdx.y, b = blockIdx.z;
  int tid = threadIdx.x;
  for(int it=0; it<4; ++it){
    int f4 = tid + it*256;               // c*16 + s4
    int c = f4>>4, s4 = f4&15;
    float4 v = *(const float4*)(h + (size_t)(b*64+c)*SPc + sj*64 + s4*4);
    *(float4*)(&lh[c*64 + s4*4]) = v;
  }
  __syncthreads();
  int osub = tid>>6, s = tid&63;
  int ob = og*40 + osub*10;
  float acc[10];
  #pragma unroll
  for(int j=0;j<10;j++) acc[j] = bias[ob+j];
  for(int c=0;c<64;c++){
    float hv = lh[c*64+s];
    #pragma unroll
    for(int j=0;j<10;j++) acc[j] = fmaf(hv, w[(ob+j)*64 + c], acc[j]);
  }
  #pragma unroll
  for(int j=0;j<10;j++){
    int o = ob+j;
    t1[(size_t)(b*320+o)*SPc + sj*64 + s] = acc[j];
    float sm = acc[j], sq = acc[j]*acc[j];
    #pragma unroll
    for(int d=1; d<64; d<<=1){ sm += __shfl_xor(sm,d); sq += __shfl_xor(sq,d); }
    if(s==0){
      pacc[o*128 + b*64 + sj]         = sm;   // P=128
      pacc[40960 + o*128 + b*64 + sj] = sq;   // CP = 320*128
    }
  }
}

// ---- finalize (out-BN only): partials -> A,B ----
__global__ void k_fin(const float* __restrict__ pacc, int P, float invN,
                      const float* __restrict__ g, const float* __restrict__ bb,
                      float* __restrict__ A, float* __restrict__ B){
  __shared__ double sh[256], sh2[256];
  int c = blockIdx.x, C = gridDim.x, tid = threadIdx.x;
  double s=0.0, s2=0.0;
  for(int p=tid; p<P; p+=256){
    s  += (double)pacc[c*P+p];
    s2 += (double)pacc[C*P + c*P + p];
  }
  sh[tid]=s; sh2[tid]=s2; __syncthreads();
  for(int off=128; off>0; off>>=1){
    if(tid<off){ sh[tid]+=sh[tid+off]; sh2[tid]+=sh2[tid+off]; }
    __syncthreads();
  }
  if(tid==0){
    float m = (float)(sh[0]*(double)invN);
    float v = (float)(sh2[0]*(double)invN) - m*m;
    float r = rsqrtf(v + EPSc);
    float gc = g[c];
    A[c] = gc*r;
    B[c] = bb[c] - m*gc*r;
  }
}

// ---- depthwise 3x3; BN1 finalized in prologue; BN2 partials out ----
__global__ void k_dw_s(const float* __restrict__ t1, const float* __restrict__ w,
                       const float* __restrict__ bias, const float* __restrict__ g1,
                       const float* __restrict__ bb1, const float* __restrict__ ap,
                       const float* __restrict__ pin, float* __restrict__ t2,
                       float* __restrict__ pout){
  int tid = threadIdx.x;
  int idx = blockIdx.x*256 + tid;
  int q = idx&63, p=(idx>>6)&63, c=(idx>>12)%C5c, b=idx/(C5c*SPc);
  __shared__ float sAB[2];
  __shared__ float ws4[4];
  {
    float v = (tid<128) ? pin[c*128 + tid] : pin[40960 + c*128 + (tid-128)];
    #pragma unroll
    for(int d=1; d<64; d<<=1) v += __shfl_xor(v, d);
    int wv = tid>>6, ln = tid&63;
    if(ln==0) ws4[wv] = v;
    __syncthreads();
    if(tid==0){
      float S = ws4[0]+ws4[1], Q = ws4[2]+ws4[3];
      float m = S*(1.f/8192.f);
      float var = Q*(1.f/8192.f) - m*m;
      float r = rsqrtf(var + EPSc);
      float gc = g1[c];
      sAB[0] = gc*r; sAB[1] = bb1[c] - m*gc*r;
    }
    __syncthreads();
  }
  float a1 = sAB[0], b1 = sAB[1], al = ap[0];
  const float* ip = t1 + (size_t)(b*C5c+c)*SPc;
  const float* wp = w + c*9;
  float acc = bias[c];
  #pragma unroll
  for(int u=0; u<3; u++){
    int pp = p+u-1; if((unsigned)pp >= 64u) continue;
    #pragma unroll
    for(int v=0; v<3; v++){
      int qq = q+v-1; if((unsigned)qq >= 64u) continue;
      float y = fmaf(ip[pp*64+qq], a1, b1);
      y = y >= 0.f ? y : al*y;
      acc = fmaf(y, wp[u*3+v], acc);
    }
  }
  t2[idx] = acc;
  float sm = acc, sq = acc*acc;
  #pragma unroll
  for(int d=1; d<64; d<<=1){ sm += __shfl_xor(sm,d); sq += __shfl_xor(sq,d); }
  __shared__ float sred[8];
  int wv = tid>>6, ln = tid&63;
  if(ln==0){ sred[wv]=sm; sred[4+wv]=sq; }
  __syncthreads();
  if(tid==0){
    float S = ((sred[0]+sred[1])+(sred[2]+sred[3]));
    float Q = ((sred[4]+sred[5])+(sred[6]+sred[7]));
    int j = blockIdx.x & 15;
    pout[c*32 + b*16 + j]         = S;   // P=32
    pout[10240 + c*32 + b*16 + j] = Q;   // CP = 320*32
  }
}

// ---- split-K 1x1 conv 320->64; BN2 finalized in prologue ----
__global__ void k_c3p(const float* __restrict__ t2, const float* __restrict__ w,
                      const float* __restrict__ g2, const float* __restrict__ bb2,
                      const float* __restrict__ ap, const float* __restrict__ pin,
                      float* __restrict__ tsp){
  __shared__ float li[80*64];     // 20 KB
  __shared__ float sA[80], sB[80];
  int sj = blockIdx.x, kk = blockIdx.y, b = blockIdx.z;
  int tid = threadIdx.x;
  if(tid < 80){
    int cg = kk*80 + tid;
    const float4* ps = (const float4*)(pin + cg*32);
    const float4* pq = (const float4*)(pin + 10240 + cg*32);
    float S=0.f, Q=0.f;
    #pragma unroll
    for(int j=0;j<8;j++){ float4 a = ps[j]; S += ((a.x+a.y)+(a.z+a.w)); }
    #pragma unroll
    for(int j=0;j<8;j++){ float4 a = pq[j]; Q += ((a.x+a.y)+(a.z+a.w)); }
    float m = S*(1.f/8192.f);
    float var = Q*(1.f/8192.f) - m*m;
    float r = rsqrtf(var + EPSc);
    float gc = g2[cg];
    sA[tid] = gc*r; sB[tid] = bb2[cg] - m*gc*r;
  }
  __syncthreads();
  float al = ap[0];
  for(int t = tid; t < 1280; t += 256){
    int c = t>>4, k4 = t&15;
    int cg = kk*80 + c;
    float4 v = *(const float4*)(t2 + (size_t)(b*C5c+cg)*SPc + sj*64 + k4*4);
    float a1 = sA[c], b1 = sB[c];
    float4 y;
    y.x = fmaf(v.x, a1, b1); y.x = y.x>=0.f ? y.x : al*y.x;
    y.y = fmaf(v.y, a1, b1); y.y = y.y>=0.f ? y.y : al*y.y;
    y.z = fmaf(v.z, a1, b1); y.z = y.z>=0.f ? y.z : al*y.z;
    y.w = fmaf(v.w, a1, b1); y.w = y.w>=0.f ? y.w : al*y.w;
    *(float4*)(&li[c*64 + k4*4]) = y;
  }
  __syncthreads();
  int og = tid>>6, s = tid&63;     // og wave-uniform
  float acc[16];
  #pragma unroll
  for(int j=0;j<16;j++) acc[j] = 0.f;
  const float* wb = w + (size_t)(og*16)*C5c + kk*80;
  for(int c=0; c<80; c++){
    float hv = li[c*64 + s];
    #pragma unroll
    for(int j=0;j<16;j++)
      acc[j] = fmaf(hv, wb[j*C5c + c], acc[j]);
  }
  float* dst = tsp + (size_t)kk*524288 + (size_t)(b*64 + og*16)*SPc + sj*64 + s;
  #pragma unroll
  for(int j=0;j<16;j++) dst[(size_t)j*SPc] = acc[j];
}

// ---- sum 4 split-K slabs + bias -> ts, emit BN3 partials ----
__global__ void k_sum(const float* __restrict__ tsp, const float* __restrict__ bias,
                      float* __restrict__ ts, float* __restrict__ pout){
  int idx = blockIdx.x*256 + threadIdx.x;
  int o = (idx>>12)&63, b = idx>>18;
  float v = bias[o];
  v += tsp[idx];
  v += tsp[524288 + idx];
  v += tsp[1048576 + idx];
  v += tsp[1572864 + idx];
  ts[idx] = v;
  float sm = v, sq = v*v;
  #pragma unroll
  for(int d=1; d<64; d<<=1){ sm += __shfl_xor(sm,d); sq += __shfl_xor(sq,d); }
  __shared__ float sred[8];
  int wv = threadIdx.x>>6, ln = threadIdx.x&63;
  if(ln==0){ sred[wv]=sm; sred[4+wv]=sq; }
  __syncthreads();
  if(threadIdx.x==0){
    float S = ((sred[0]+sred[1])+(sred[2]+sred[3]));
    float Q = ((sred[4]+sred[5])+(sred[6]+sred[7]));
    int j = blockIdx.x & 15;
    pout[o*32 + b*16 + j]        = S;   // P=32
    pout[2048 + o*32 + b*16 + j] = Q;   // CP = 64*32
  }
}

// ---- BN3 (finalized in prologue) + PReLU3 + residual add into h ----
__global__ void k_addres(const float* __restrict__ ts, float* __restrict__ h,
                         const float* __restrict__ g3, const float* __restrict__ bb3,
                         const float* __restrict__ ap, const float* __restrict__ pin){
  int tid = threadIdx.x;
  int idx = blockIdx.x*256 + tid;
  int c = (idx>>12)&63;              // constant per block
  __shared__ float sAB[2];
  if(tid < 64){
    float v = (tid<32) ? pin[c*32 + tid] : pin[2048 + c*32 + (tid-32)];
    #pragma unroll
    for(int d=1; d<32; d<<=1) v += __shfl_xor(v, d);
    float S = __shfl(v, 0);
    float Q = __shfl(v, 32);
    if(tid==0){
      float m = S*(1.f/8192.f);
      float var = Q*(1.f/8192.f) - m*m;
      float r = rsqrtf(var + EPSc);
      float gc = g3[c];
      sAB[0] = gc*r; sAB[1] = bb3[c] - m*gc*r;
    }
  }
  __syncthreads();
  float y = fmaf(ts[idx], sAB[0], sAB[1]);
  float al = ap[0];
  y = y >= 0.f ? y : al*y;
  h[idx] += y;
}

// ---- head 1x1 conv (64->512) writing z-innermost gvol, chunk=[k2][o16][z64] ----
__global__ void k_head_t(const float* __restrict__ h, const float* __restrict__ w,
                         const float* __restrict__ bias, float* __restrict__ gv){
  __shared__ float sb0[64*65], sb1[64*65];
  int bid = blockIdx.x;            // (b*16 + o)*16 + ci
  int ci = bid & 15, o = (bid>>4) & 15, b = bid >> 8;
  int c0 = (o*16 + ci)*2, c1 = c0 + 1;
  const float* hp0 = h + (size_t)b*HIDc*SPc;
  const float* w0 = w + (size_t)c0*HIDc;
  const float* w1 = w + (size_t)c1*HIDc;
  float b0 = bias[c0], b1 = bias[c1];
  int tid = threadIdx.x;
  for(int j=0; j<16; j++){
    int s = tid + j*256;           // s = p*64 + q
    float a0 = b0, a1 = b1;
    #pragma unroll 8
    for(int kc=0; kc<HIDc; kc++){
      float hv = hp0[kc*SPc + s];
      a0 = fmaf(hv, w0[kc], a0);
      a1 = fmaf(hv, w1[kc], a1);
    }
    int pad = s + (s>>6);
    sb0[pad] = a0; sb1[pad] = a1;
  }
  __syncthreads();
  float* gb = gv + (size_t)b*(64*16*2048);
  for(int j=0; j<16; j++){
    int t = tid + j*256;
    int q = t>>6, p = t&63;
    size_t base = ((size_t)(q*16 + ci))*2048 + (size_t)o*64 + p;
    gb[base]        = sb0[p*65 + q];   // k=0 weight plane
    gb[base + 1024] = sb1[p*65 + q];   // k=1 bias plane
  }
}

// ---- slice v3: 1 row x 16 cols/block; y-blend at staging; b64 z-pairs ----
__global__ void k_slice(const float* __restrict__ x, const float* __restrict__ gv,
                        float* __restrict__ outp, float* __restrict__ pacc){
  __shared__ float lds[12480];
  int xseg = blockIdx.x, hp = blockIdx.y, b = blockIdx.z;
  int tid = threadIdx.x;
  const float* gb = gv + (size_t)b*(64*16*2048);
  int y0 = (hp*63)/255;
  int y1 = min(y0+1, 63);
  float fy = hp*(63.f/255.f) - (float)y0;
  int xbase = (xseg*240)/255;

  if(tid < 96){
    int cix = tid >> 5, r = tid & 31;
    int k = r >> 4, o = r & 15;
    int xs = min(xbase + cix, 15);
    const float4* s0 = (const float4*)(gb + (size_t)(y0*16+xs)*2048 + k*1024 + o*64);
    const float4* s1 = (const float4*)(gb + (size_t)(y1*16+xs)*2048 + k*1024 + o*64);
    float2* d = (float2*)lds + cix*2080 + k*1040 + o*65;
    float prev = 0.f;
    #pragma unroll
    for(int j=0; j<16; ++j){
      float4 a = s0[j], c = s1[j];
      float b0 = fmaf(fy, c.x-a.x, a.x);
      float b1 = fmaf(fy, c.y-a.y, a.y);
      float b2 = fmaf(fy, c.z-a.z, a.z);
      float b3 = fmaf(fy, c.w-a.w, a.w);
      if(j) d[4*j-1] = make_float2(prev, b0);
      d[4*j]   = make_float2(b0, b1);
      d[4*j+1] = make_float2(b1, b2);
      d[4*j+2] = make_float2(b2, b3);
      prev = b3;
    }
    d[63] = make_float2(prev, prev);
  }
  __syncthreads();

  int wv = tid>>6, lane = tid&63;
  int o = lane>>2, pl = lane&3;
  int lc = wv*4 + pl;
  int wq = xseg*16 + lc;

  int x0 = (wq*15)/255;
  float fx = wq*(15.f/255.f) - (float)x0;
  int x1 = min(x0+1, 15);
  int cA = (x0 - xbase)*2080, cB = (x1 - xbase)*2080;
  float cwA = 1.f-fx, cwB = fx;
  int obase = o*65;
  const float2* l2 = (const float2*)lds;

  float acc = 0.f, bacc = 0.f;
  for(int i=0; i<CIc; i++){
    float xv = x[((size_t)(b*CIc+i)*Hc + hp)*Wc + wq];
    float g = fminf(fmaxf(xv, 0.f), 1.f);
    float pz = g*63.f;
    int z0 = (int)pz; float fz = pz - (float)z0;
    float wz0 = cwA*(1.f-fz), wz1 = cwA*fz;
    float vz0 = cwB*(1.f-fz), vz1 = cwB*fz;
    int aA = cA + obase + z0, aB = cB + obase + z0;
    float2 wA = l2[aA],        wB = l2[aB];
    float2 bA = l2[aA + 1040], bB = l2[aB + 1040];
    float wsum = fmaf(wz0, wA.x, fmaf(wz1, wA.y, fmaf(vz0, wB.x, vz1*wB.y)));
    float bsum = fmaf(wz0, bA.x, fmaf(wz1, bA.y, fmaf(vz0, bB.x, vz1*bB.y)));
    acc  = fmaf(xv, wsum, acc);
    bacc += bsum;
  }
  float vout = acc + bacc*(1.f/16.f);
  outp[((size_t)(b*COc+o)*Hc + hp)*Wc + wq] = vout;

  float sm = vout, sq = vout*vout;
  sm += __shfl_xor(sm,1); sq += __shfl_xor(sq,1);
  sm += __shfl_xor(sm,2); sq += __shfl_xor(sq,2);
  __syncthreads();
  if(pl==0){ lds[(wv*16+o)*2] = sm; lds[(wv*16+o)*2+1] = sq; }
  __syncthreads();
  if(tid < 32){
    int oo = tid>>1, kd = tid&1;
    float S = ((lds[(0*16+oo)*2+kd] + lds[(1*16+oo)*2+kd])
             + (lds[(2*16+oo)*2+kd] + lds[(3*16+oo)*2+kd]));
    int blk = (b*256 + hp)*16 + xseg;       // P=8192
    pacc[kd*131072 + oo*8192 + blk] = S;    // CP = 16*8192
  }
}

// ---- final BN + SiLU in place on d_out ----
__global__ void k_final(float* __restrict__ out, const float* __restrict__ A,
                        const float* __restrict__ B){
  int idx = blockIdx.x*256 + threadIdx.x;
  int c = (idx>>16)&15;
  float y = fmaf(out[idx], A[c], B[c]);
  out[idx] = y / (1.f + expf(-y));
}

} // namespace

extern "C" void kernel_launch(void* const* d_in, const int* in_sizes, int n_in,
                              void* d_out, int out_size, void* d_ws, size_t ws_size,
                              hipStream_t stream){
  const float* x       = (const float*)d_in[0];
  const float* conv0_w = (const float*)d_in[1];
  const float* conv0_b = (const float*)d_in[2];
  const float* prelu0  = (const float*)d_in[3];
  const float* c1w  = (const float*)d_in[4];
  const float* c1b  = (const float*)d_in[5];
  const float* bn1g = (const float*)d_in[6];
  const float* bn1b = (const float*)d_in[7];
  const float* p1   = (const float*)d_in[8];
  const float* dww  = (const float*)d_in[9];
  const float* dwb  = (const float*)d_in[10];
  const float* bn2g = (const float*)d_in[11];
  const float* bn2b = (const float*)d_in[12];
  const float* p2   = (const float*)d_in[13];
  const float* c3w  = (const float*)d_in[14];
  const float* c3b  = (const float*)d_in[15];
  const float* bn3g = (const float*)d_in[16];
  const float* bn3b = (const float*)d_in[17];
  const float* p3   = (const float*)d_in[18];
  const float* hw   = (const float*)d_in[19];
  const float* hb   = (const float*)d_in[20];
  const float* obg  = (const float*)d_in[21];
  const float* obb  = (const float*)d_in[22];
  float* out = (float*)d_out;
  float* ws  = (float*)d_ws;

  // workspace (floats)
  float* xd    = ws;                 // 131072
  float* h     = xd + 131072;        // 524288
  float* A     = h  + 524288;        // 320
  float* B     = A  + 320;           // 320
  float* pacc  = B  + 320;           // 81920  BN1 partials (k_c1 -> k_dw_s)
  float* paccb = pacc + 81920;       // 20480  BN2 partials (k_dw_s -> k_c3p)
  float* paccc = paccb + 20480;      // 4096   BN3 partials (k_sum -> k_addres)
  float* t1    = paccc + 4096;       // 2621440
  float* t2    = t1 + 2621440;       // 2621440
  float* ts    = t2 + 2621440;       // 524288
  float* gv    = t1;                 // 4194304 aliases t1+t2 (dead by head)
  float* tsp   = t1;                 // 2097152 split-K slabs alias t1
  float* pacc2 = ts;                 // 262144 slice partials alias ts

  k_down <<<512,  256, 0, stream>>>(x, xd);
  k_conv0<<<2048, 256, 0, stream>>>(xd, conv0_w, conv0_b, prelu0, h);

  for(int i=0; i<3; i++){
    k_c1  <<<dim3(8,64,Bn), 256, 0, stream>>>(h, c1w + i*20480, c1b + i*320, t1, pacc);
    k_dw_s<<<10240, 256, 0, stream>>>(t1, dww + i*2880, dwb + i*320,
                                      bn1g+i*320, bn1b+i*320, p1+i, pacc, t2, paccb);
    k_c3p <<<dim3(64,4,Bn), 256, 0, stream>>>(t2, c3w + i*20480,
                                              bn2g+i*320, bn2b+i*320, p2+i, paccb, tsp);
    k_sum <<<2048, 256, 0, stream>>>(tsp, c3b + i*64, ts, paccc);
    k_addres<<<2048, 256, 0, stream>>>(ts, h, bn3g+i*64, bn3b+i*64, p3+i, paccc);
  }

  k_head_t<<<512, 256, 0, stream>>>(h, hw, hb, gv);
  k_slice <<<dim3(16,256,Bn), 256, 0, stream>>>(x, gv, out, pacc2);
  k_fin   <<<16, 256, 0, stream>>>(pacc2, 8192, 1.f/131072.f, obg, obb, A, B);
  k_final <<<8192, 256, 0, stream>>>(out, A, B);
}

// Round 15
// 509.154 us; speedup vs baseline: 1.3572x; 1.0219x over previous
//
#include <hip/hip_runtime.h>
#include <math.h>

namespace {

constexpr int Bn=2, CIc=16, COc=16, Hc=256, Wc=256, HIDc=64, C5c=320;
constexpr int SPc = 4096;               // 64*64
constexpr float EPSc = 1e-5f;

// ---- 4x4 mean downsample: x (B,16,256,256) -> xd (B,16,64,64) ----
__global__ void k_down(const float* __restrict__ x, float* __restrict__ xd){
  int idx = blockIdx.x*blockDim.x + threadIdx.x;
  if (idx >= Bn*CIc*SPc) return;
  int q = idx & 63, p = (idx>>6)&63, c = idx>>12;
  const float* xp = x + ((size_t)c*Hc + p*4)*Wc + q*4;
  float s = 0.f;
  #pragma unroll
  for(int dy=0; dy<4; dy++)
    #pragma unroll
    for(int dx=0; dx<4; dx++) s += xp[dy*Wc+dx];
  xd[idx] = s * (1.f/16.f);
}

// ---- conv0 3x3 pad1 (16->64) + scalar PReLU ----
__global__ void k_conv0(const float* __restrict__ xd, const float* __restrict__ w,
                        const float* __restrict__ bias, const float* __restrict__ a0,
                        float* __restrict__ h){
  int idx = blockIdx.x*blockDim.x + threadIdx.x;
  if (idx >= Bn*HIDc*SPc) return;
  int q = idx&63, p=(idx>>6)&63, co=(idx>>12)&63, b=idx/(HIDc*SPc);
  float acc = bias[co];
  for(int ci=0; ci<CIc; ci++){
    const float* xp = xd + (size_t)(b*CIc+ci)*SPc;
    const float* wp = w + (co*CIc+ci)*9;
    #pragma unroll
    for(int u=0; u<3; u++){
      int pp = p+u-1; if((unsigned)pp >= 64u) continue;
      #pragma unroll
      for(int v=0; v<3; v++){
        int qq = q+v-1; if((unsigned)qq >= 64u) continue;
        acc = fmaf(xp[pp*64+qq], wp[u*3+v], acc);
      }
    }
  }
  float a = a0[0];
  h[idx] = acc >= 0.f ? acc : a*acc;
}

// ---- fused 1x1 conv 64->320 + BN1 stat partials ----
__global__ void k_c1(const float* __restrict__ h, const float* __restrict__ w,
                     const float* __restrict__ bias, float* __restrict__ t1,
                     float* __restrict__ pacc){
  __shared__ float lh[64*64];
  int og = blockIdx.x, sj = blockIdx.y, b = blockIdx.z;
  int tid = threadIdx.x;
  for(int it=0; it<4; ++it){
    int f4 = tid + it*256;               // c*16 + s4
    int c = f4>>4, s4 = f4&15;
    float4 v = *(const float4*)(h + (size_t)(b*64+c)*SPc + sj*64 + s4*4);
    *(float4*)(&lh[c*64 + s4*4]) = v;
  }
  __syncthreads();
  int osub = tid>>6, s = tid&63;
  int ob = og*40 + osub*10;
  float acc[10];
  #pragma unroll
  for(int j=0;j<10;j++) acc[j] = bias[ob+j];
  for(int c=0;c<64;c++){
    float hv = lh[c*64+s];
    #pragma unroll
    for(int j=0;j<10;j++) acc[j] = fmaf(hv, w[(ob+j)*64 + c], acc[j]);
  }
  #pragma unroll
  for(int j=0;j<10;j++){
    int o = ob+j;
    t1[(size_t)(b*320+o)*SPc + sj*64 + s] = acc[j];
    float sm = acc[j], sq = acc[j]*acc[j];
    #pragma unroll
    for(int d=1; d<64; d<<=1){ sm += __shfl_xor(sm,d); sq += __shfl_xor(sq,d); }
    if(s==0){
      pacc[o*128 + b*64 + sj]         = sm;   // P=128
      pacc[40960 + o*128 + b*64 + sj] = sq;   // CP = 320*128
    }
  }
}

// ---- finalize (out-BN only): partials -> A,B ----
__global__ void k_fin(const float* __restrict__ pacc, int P, float invN,
                      const float* __restrict__ g, const float* __restrict__ bb,
                      float* __restrict__ A, float* __restrict__ B){
  __shared__ double sh[256], sh2[256];
  int c = blockIdx.x, C = gridDim.x, tid = threadIdx.x;
  double s=0.0, s2=0.0;
  for(int p=tid; p<P; p+=256){
    s  += (double)pacc[c*P+p];
    s2 += (double)pacc[C*P + c*P + p];
  }
  sh[tid]=s; sh2[tid]=s2; __syncthreads();
  for(int off=128; off>0; off>>=1){
    if(tid<off){ sh[tid]+=sh[tid+off]; sh2[tid]+=sh2[tid+off]; }
    __syncthreads();
  }
  if(tid==0){
    float m = (float)(sh[0]*(double)invN);
    float v = (float)(sh2[0]*(double)invN) - m*m;
    float r = rsqrtf(v + EPSc);
    float gc = g[c];
    A[c] = gc*r;
    B[c] = bb[c] - m*gc*r;
  }
}

// ---- depthwise 3x3; BN1 finalized in prologue; BN2 partials out ----
__global__ void k_dw_s(const float* __restrict__ t1, const float* __restrict__ w,
                       const float* __restrict__ bias, const float* __restrict__ g1,
                       const float* __restrict__ bb1, const float* __restrict__ ap,
                       const float* __restrict__ pin, float* __restrict__ t2,
                       float* __restrict__ pout){
  int tid = threadIdx.x;
  int idx = blockIdx.x*256 + tid;
  int q = idx&63, p=(idx>>6)&63, c=(idx>>12)%C5c, b=idx/(C5c*SPc);
  __shared__ float sAB[2];
  __shared__ float ws4[4];
  {
    float v = (tid<128) ? pin[c*128 + tid] : pin[40960 + c*128 + (tid-128)];
    #pragma unroll
    for(int d=1; d<64; d<<=1) v += __shfl_xor(v, d);
    int wv = tid>>6, ln = tid&63;
    if(ln==0) ws4[wv] = v;
    __syncthreads();
    if(tid==0){
      float S = ws4[0]+ws4[1], Q = ws4[2]+ws4[3];
      float m = S*(1.f/8192.f);
      float var = Q*(1.f/8192.f) - m*m;
      float r = rsqrtf(var + EPSc);
      float gc = g1[c];
      sAB[0] = gc*r; sAB[1] = bb1[c] - m*gc*r;
    }
    __syncthreads();
  }
  float a1 = sAB[0], b1 = sAB[1], al = ap[0];
  const float* ip = t1 + (size_t)(b*C5c+c)*SPc;
  const float* wp = w + c*9;
  float acc = bias[c];
  #pragma unroll
  for(int u=0; u<3; u++){
    int pp = p+u-1; if((unsigned)pp >= 64u) continue;
    #pragma unroll
    for(int v=0; v<3; v++){
      int qq = q+v-1; if((unsigned)qq >= 64u) continue;
      float y = fmaf(ip[pp*64+qq], a1, b1);
      y = y >= 0.f ? y : al*y;
      acc = fmaf(y, wp[u*3+v], acc);
    }
  }
  t2[idx] = acc;
  float sm = acc, sq = acc*acc;
  #pragma unroll
  for(int d=1; d<64; d<<=1){ sm += __shfl_xor(sm,d); sq += __shfl_xor(sq,d); }
  __shared__ float sred[8];
  int wv = tid>>6, ln = tid&63;
  if(ln==0){ sred[wv]=sm; sred[4+wv]=sq; }
  __syncthreads();
  if(tid==0){
    float S = ((sred[0]+sred[1])+(sred[2]+sred[3]));
    float Q = ((sred[4]+sred[5])+(sred[6]+sred[7]));
    int j = blockIdx.x & 15;
    pout[c*32 + b*16 + j]         = S;   // P=32
    pout[10240 + c*32 + b*16 + j] = Q;   // CP = 320*32
  }
}

// ---- split-K 1x1 conv 320->64; BN2 finalized in prologue ----
__global__ void k_c3p(const float* __restrict__ t2, const float* __restrict__ w,
                      const float* __restrict__ g2, const float* __restrict__ bb2,
                      const float* __restrict__ ap, const float* __restrict__ pin,
                      float* __restrict__ tsp){
  __shared__ float li[80*64];     // 20 KB
  __shared__ float sA[80], sB[80];
  int sj = blockIdx.x, kk = blockIdx.y, b = blockIdx.z;
  int tid = threadIdx.x;
  if(tid < 80){
    int cg = kk*80 + tid;
    const float4* ps = (const float4*)(pin + cg*32);
    const float4* pq = (const float4*)(pin + 10240 + cg*32);
    float S=0.f, Q=0.f;
    #pragma unroll
    for(int j=0;j<8;j++){ float4 a = ps[j]; S += ((a.x+a.y)+(a.z+a.w)); }
    #pragma unroll
    for(int j=0;j<8;j++){ float4 a = pq[j]; Q += ((a.x+a.y)+(a.z+a.w)); }
    float m = S*(1.f/8192.f);
    float var = Q*(1.f/8192.f) - m*m;
    float r = rsqrtf(var + EPSc);
    float gc = g2[cg];
    sA[tid] = gc*r; sB[tid] = bb2[cg] - m*gc*r;
  }
  __syncthreads();
  float al = ap[0];
  for(int t = tid; t < 1280; t += 256){
    int c = t>>4, k4 = t&15;
    int cg = kk*80 + c;
    float4 v = *(const float4*)(t2 + (size_t)(b*C5c+cg)*SPc + sj*64 + k4*4);
    float a1 = sA[c], b1 = sB[c];
    float4 y;
    y.x = fmaf(v.x, a1, b1); y.x = y.x>=0.f ? y.x : al*y.x;
    y.y = fmaf(v.y, a1, b1); y.y = y.y>=0.f ? y.y : al*y.y;
    y.z = fmaf(v.z, a1, b1); y.z = y.z>=0.f ? y.z : al*y.z;
    y.w = fmaf(v.w, a1, b1); y.w = y.w>=0.f ? y.w : al*y.w;
    *(float4*)(&li[c*64 + k4*4]) = y;
  }
  __syncthreads();
  int og = tid>>6, s = tid&63;     // og wave-uniform
  float acc[16];
  #pragma unroll
  for(int j=0;j<16;j++) acc[j] = 0.f;
  const float* wb = w + (size_t)(og*16)*C5c + kk*80;
  for(int c=0; c<80; c++){
    float hv = li[c*64 + s];
    #pragma unroll
    for(int j=0;j<16;j++)
      acc[j] = fmaf(hv, wb[j*C5c + c], acc[j]);
  }
  float* dst = tsp + (size_t)kk*524288 + (size_t)(b*64 + og*16)*SPc + sj*64 + s;
  #pragma unroll
  for(int j=0;j<16;j++) dst[(size_t)j*SPc] = acc[j];
}

// ---- sum 4 split-K slabs + bias -> ts, emit BN3 partials ----
__global__ void k_sum(const float* __restrict__ tsp, const float* __restrict__ bias,
                      float* __restrict__ ts, float* __restrict__ pout){
  int idx = blockIdx.x*256 + threadIdx.x;
  int o = (idx>>12)&63, b = idx>>18;
  float v = bias[o];
  v += tsp[idx];
  v += tsp[524288 + idx];
  v += tsp[1048576 + idx];
  v += tsp[1572864 + idx];
  ts[idx] = v;
  float sm = v, sq = v*v;
  #pragma unroll
  for(int d=1; d<64; d<<=1){ sm += __shfl_xor(sm,d); sq += __shfl_xor(sq,d); }
  __shared__ float sred[8];
  int wv = threadIdx.x>>6, ln = threadIdx.x&63;
  if(ln==0){ sred[wv]=sm; sred[4+wv]=sq; }
  __syncthreads();
  if(threadIdx.x==0){
    float S = ((sred[0]+sred[1])+(sred[2]+sred[3]));
    float Q = ((sred[4]+sred[5])+(sred[6]+sred[7]));
    int j = blockIdx.x & 15;
    pout[o*32 + b*16 + j]        = S;   // P=32
    pout[2048 + o*32 + b*16 + j] = Q;   // CP = 64*32
  }
}

// ---- BN3 (finalized in prologue) + PReLU3 + residual add into h ----
__global__ void k_addres(const float* __restrict__ ts, float* __restrict__ h,
                         const float* __restrict__ g3, const float* __restrict__ bb3,
                         const float* __restrict__ ap, const float* __restrict__ pin){
  int tid = threadIdx.x;
  int idx = blockIdx.x*256 + tid;
  int c = (idx>>12)&63;              // constant per block
  __shared__ float sAB[2];
  if(tid < 64){
    float v = (tid<32) ? pin[c*32 + tid] : pin[2048 + c*32 + (tid-32)];
    #pragma unroll
    for(int d=1; d<32; d<<=1) v += __shfl_xor(v, d);
    float S = __shfl(v, 0);
    float Q = __shfl(v, 32);
    if(tid==0){
      float m = S*(1.f/8192.f);
      float var = Q*(1.f/8192.f) - m*m;
      float r = rsqrtf(var + EPSc);
      float gc = g3[c];
      sAB[0] = gc*r; sAB[1] = bb3[c] - m*gc*r;
    }
  }
  __syncthreads();
  float y = fmaf(ts[idx], sAB[0], sAB[1]);
  float al = ap[0];
  y = y >= 0.f ? y : al*y;
  h[idx] += y;
}

// ---- head 1x1 conv (64->512) writing z-innermost gvol, chunk=[k2][o16][z64] ----
__global__ void k_head_t(const float* __restrict__ h, const float* __restrict__ w,
                         const float* __restrict__ bias, float* __restrict__ gv){
  __shared__ float sb0[64*65], sb1[64*65];
  int bid = blockIdx.x;            // (b*16 + o)*16 + ci
  int ci = bid & 15, o = (bid>>4) & 15, b = bid >> 8;
  int c0 = (o*16 + ci)*2, c1 = c0 + 1;
  const float* hp0 = h + (size_t)b*HIDc*SPc;
  const float* w0 = w + (size_t)c0*HIDc;
  const float* w1 = w + (size_t)c1*HIDc;
  float b0 = bias[c0], b1 = bias[c1];
  int tid = threadIdx.x;
  for(int j=0; j<16; j++){
    int s = tid + j*256;           // s = p*64 + q
    float a0 = b0, a1 = b1;
    #pragma unroll 8
    for(int kc=0; kc<HIDc; kc++){
      float hv = hp0[kc*SPc + s];
      a0 = fmaf(hv, w0[kc], a0);
      a1 = fmaf(hv, w1[kc], a1);
    }
    int pad = s + (s>>6);
    sb0[pad] = a0; sb1[pad] = a1;
  }
  __syncthreads();
  float* gb = gv + (size_t)b*(64*16*2048);
  for(int j=0; j<16; j++){
    int t = tid + j*256;
    int q = t>>6, p = t&63;
    size_t base = ((size_t)(q*16 + ci))*2048 + (size_t)o*64 + p;
    gb[base]        = sb0[p*65 + q];   // k=0 weight plane
    gb[base + 1024] = sb1[p*65 + q];   // k=1 bias plane
  }
}

// ---- slice v4: 17-col segments (x0 block-uniform), 1 row/block, 320 thr,
// 2-chunk staging (32.5 KB LDS), y-blend at staging, b64 z-pairs ----
// grid (16 xseg, 256 row, Bn); seg 0..14 cover 17 px, seg 15 covers px 255.
__global__ void k_slice(const float* __restrict__ x, const float* __restrict__ gv,
                        float* __restrict__ outp, float* __restrict__ pacc){
  __shared__ float lds[8320];     // 4160 float2
  int xseg = blockIdx.x, hp = blockIdx.y, b = blockIdx.z;
  int tid = threadIdx.x;
  const float* gb = gv + (size_t)b*(64*16*2048);
  int y0 = (hp*63)/255;
  int y1 = min(y0+1, 63);
  float fy = hp*(63.f/255.f) - (float)y0;

  // stage + y-blend: 128 threads, each owns half a (chunk,k,o) z-line
  if(tid < 128){
    int half = tid & 1, o = (tid>>1)&15, k = (tid>>5)&1, cix = (tid>>6)&1;
    int xs = min(xseg + cix, 15);
    const float* b0p = gb + (size_t)(y0*16+xs)*2048 + k*1024 + o*64;
    const float* b1p = gb + (size_t)(y1*16+xs)*2048 + k*1024 + o*64;
    float2* d = (float2*)lds + cix*2080 + k*1040 + o*65;
    float prev = 0.f;
    if(half){
      float a = b0p[31], c = b1p[31];
      prev = fmaf(fy, c-a, a);
    }
    int j0 = half*8;
    #pragma unroll
    for(int j=0; j<8; ++j){
      int jj = j0 + j;
      float4 a = *(const float4*)(b0p + jj*4);
      float4 c = *(const float4*)(b1p + jj*4);
      float v0 = fmaf(fy, c.x-a.x, a.x);
      float v1 = fmaf(fy, c.y-a.y, a.y);
      float v2 = fmaf(fy, c.z-a.z, a.z);
      float v3 = fmaf(fy, c.w-a.w, a.w);
      if(j > 0 || half) d[4*jj-1] = make_float2(prev, v0);
      d[4*jj]   = make_float2(v0, v1);
      d[4*jj+1] = make_float2(v1, v2);
      d[4*jj+2] = make_float2(v2, v3);
      prev = v3;
    }
    if(half) d[63] = make_float2(prev, prev);
  }
  __syncthreads();

  int wv = tid>>6, lane = tid&63;
  int o = lane>>2, pl = lane&3;
  int lc = wv*4 + pl;               // 0..19 (17+ invalid)
  int wq = xseg*17 + lc;
  bool act = (lc < 17) && (wq < 256);
  int wqc = min(wq, 255);

  float fx = (float)lc * (1.f/17.f);
  float cwA = 1.f - fx, cwB = fx;
  int obase = o*65;
  const float2* l2 = (const float2*)lds;

  float acc = 0.f, bacc = 0.f;
  for(int i=0; i<CIc; i++){
    float xv = x[((size_t)(b*CIc+i)*Hc + hp)*Wc + wqc];
    float g = fminf(fmaxf(xv, 0.f), 1.f);
    float pz = g*63.f;
    int z0 = (int)pz; float fz = pz - (float)z0;
    float wz0 = cwA*(1.f-fz), wz1 = cwA*fz;
    float vz0 = cwB*(1.f-fz), vz1 = cwB*fz;
    int aA = obase + z0, aB = 2080 + obase + z0;
    float2 wA = l2[aA],        wB = l2[aB];
    float2 bA = l2[aA + 1040], bB = l2[aB + 1040];
    float wsum = fmaf(wz0, wA.x, fmaf(wz1, wA.y, fmaf(vz0, wB.x, vz1*wB.y)));
    float bsum = fmaf(wz0, bA.x, fmaf(wz1, bA.y, fmaf(vz0, bB.x, vz1*bB.y)));
    acc  = fmaf(xv, wsum, acc);
    bacc += bsum;
  }
  float vout = act ? (acc + bacc*(1.f/16.f)) : 0.f;
  if(act)
    outp[((size_t)(b*COc+o)*Hc + hp)*Wc + wq] = vout;

  // deterministic stats: 4 px in wave, then 5 waves via LDS
  float sm = vout, sq = vout*vout;
  sm += __shfl_xor(sm,1); sq += __shfl_xor(sq,1);
  sm += __shfl_xor(sm,2); sq += __shfl_xor(sq,2);
  __syncthreads();
  if(pl==0){ lds[(wv*16+o)*2] = sm; lds[(wv*16+o)*2+1] = sq; }
  __syncthreads();
  if(tid < 32){
    int oo = tid>>1, kd = tid&1;
    float S = (((lds[(0*16+oo)*2+kd] + lds[(1*16+oo)*2+kd])
             +  (lds[(2*16+oo)*2+kd] + lds[(3*16+oo)*2+kd]))
             +   lds[(4*16+oo)*2+kd]);
    int blk = (b*256 + hp)*16 + xseg;       // P=8192
    pacc[kd*131072 + oo*8192 + blk] = S;    // CP = 16*8192
  }
}

// ---- final BN + SiLU in place on d_out ----
__global__ void k_final(float* __restrict__ out, const float* __restrict__ A,
                        const float* __restrict__ B){
  int idx = blockIdx.x*256 + threadIdx.x;
  int c = (idx>>16)&15;
  float y = fmaf(out[idx], A[c], B[c]);
  out[idx] = y / (1.f + expf(-y));
}

} // namespace

extern "C" void kernel_launch(void* const* d_in, const int* in_sizes, int n_in,
                              void* d_out, int out_size, void* d_ws, size_t ws_size,
                              hipStream_t stream){
  const float* x       = (const float*)d_in[0];
  const float* conv0_w = (const float*)d_in[1];
  const float* conv0_b = (const float*)d_in[2];
  const float* prelu0  = (const float*)d_in[3];
  const float* c1w  = (const float*)d_in[4];
  const float* c1b  = (const float*)d_in[5];
  const float* bn1g = (const float*)d_in[6];
  const float* bn1b = (const float*)d_in[7];
  const float* p1   = (const float*)d_in[8];
  const float* dww  = (const float*)d_in[9];
  const float* dwb  = (const float*)d_in[10];
  const float* bn2g = (const float*)d_in[11];
  const float* bn2b = (const float*)d_in[12];
  const float* p2   = (const float*)d_in[13];
  const float* c3w  = (const float*)d_in[14];
  const float* c3b  = (const float*)d_in[15];
  const float* bn3g = (const float*)d_in[16];
  const float* bn3b = (const float*)d_in[17];
  const float* p3   = (const float*)d_in[18];
  const float* hw   = (const float*)d_in[19];
  const float* hb   = (const float*)d_in[20];
  const float* obg  = (const float*)d_in[21];
  const float* obb  = (const float*)d_in[22];
  float* out = (float*)d_out;
  float* ws  = (float*)d_ws;

  // workspace (floats)
  float* xd    = ws;                 // 131072
  float* h     = xd + 131072;        // 524288
  float* A     = h  + 524288;        // 320
  float* B     = A  + 320;           // 320
  float* pacc  = B  + 320;           // 81920  BN1 partials (k_c1 -> k_dw_s)
  float* paccb = pacc + 81920;       // 20480  BN2 partials (k_dw_s -> k_c3p)
  float* paccc = paccb + 20480;      // 4096   BN3 partials (k_sum -> k_addres)
  float* t1    = paccc + 4096;       // 2621440
  float* t2    = t1 + 2621440;       // 2621440
  float* ts    = t2 + 2621440;       // 524288
  float* gv    = t1;                 // 4194304 aliases t1+t2 (dead by head)
  float* tsp   = t1;                 // 2097152 split-K slabs alias t1
  float* pacc2 = ts;                 // 262144 slice partials alias ts

  k_down <<<512,  256, 0, stream>>>(x, xd);
  k_conv0<<<2048, 256, 0, stream>>>(xd, conv0_w, conv0_b, prelu0, h);

  for(int i=0; i<3; i++){
    k_c1  <<<dim3(8,64,Bn), 256, 0, stream>>>(h, c1w + i*20480, c1b + i*320, t1, pacc);
    k_dw_s<<<10240, 256, 0, stream>>>(t1, dww + i*2880, dwb + i*320,
                                      bn1g+i*320, bn1b+i*320, p1+i, pacc, t2, paccb);
    k_c3p <<<dim3(64,4,Bn), 256, 0, stream>>>(t2, c3w + i*20480,
                                              bn2g+i*320, bn2b+i*320, p2+i, paccb, tsp);
    k_sum <<<2048, 256, 0, stream>>>(tsp, c3b + i*64, ts, paccc);
    k_addres<<<2048, 256, 0, stream>>>(ts, h, bn3g+i*64, bn3b+i*64, p3+i, paccc);
  }

  k_head_t<<<512, 256, 0, stream>>>(h, hw, hb, gv);
  k_slice <<<dim3(16,256,Bn), 320, 0, stream>>>(x, gv, out, pacc2);
  k_fin   <<<16, 256, 0, stream>>>(pacc2, 8192, 1.f/131072.f, obg, obb, A, B);
  k_final <<<8192, 256, 0, stream>>>(out, A, B);
}

// Round 17
// 457.561 us; speedup vs baseline: 1.5102x; 1.1128x over previous
//
#include <hip/hip_runtime.h>
#include <math.h>

namespace {

constexpr int Bn=2, CIc=16, COc=16, Hc=256, Wc=256, HIDc=64, C5c=320;
constexpr int SPc = 4096;               // 64*64
constexpr float EPSc = 1e-5f;

// ---- 4x4 mean downsample: x (B,16,256,256) -> xd (B,16,64,64) ----
__global__ void k_down(const float* __restrict__ x, float* __restrict__ xd){
  int idx = blockIdx.x*blockDim.x + threadIdx.x;
  if (idx >= Bn*CIc*SPc) return;
  int q = idx & 63, p = (idx>>6)&63, c = idx>>12;
  const float* xp = x + ((size_t)c*Hc + p*4)*Wc + q*4;
  float s = 0.f;
  #pragma unroll
  for(int dy=0; dy<4; dy++)
    #pragma unroll
    for(int dx=0; dx<4; dx++) s += xp[dy*Wc+dx];
  xd[idx] = s * (1.f/16.f);
}

// ---- conv0 3x3 pad1 (16->64) + scalar PReLU ----
__global__ void k_conv0(const float* __restrict__ xd, const float* __restrict__ w,
                        const float* __restrict__ bias, const float* __restrict__ a0,
                        float* __restrict__ h){
  int idx = blockIdx.x*blockDim.x + threadIdx.x;
  if (idx >= Bn*HIDc*SPc) return;
  int q = idx&63, p=(idx>>6)&63, co=(idx>>12)&63, b=idx/(HIDc*SPc);
  float acc = bias[co];
  for(int ci=0; ci<CIc; ci++){
    const float* xp = xd + (size_t)(b*CIc+ci)*SPc;
    const float* wp = w + (co*CIc+ci)*9;
    #pragma unroll
    for(int u=0; u<3; u++){
      int pp = p+u-1; if((unsigned)pp >= 64u) continue;
      #pragma unroll
      for(int v=0; v<3; v++){
        int qq = q+v-1; if((unsigned)qq >= 64u) continue;
        acc = fmaf(xp[pp*64+qq], wp[u*3+v], acc);
      }
    }
  }
  float a = a0[0];
  h[idx] = acc >= 0.f ? acc : a*acc;
}

// ---- fused 1x1 conv 64->320 + BN1 stat partials ----
__global__ void k_c1(const float* __restrict__ h, const float* __restrict__ w,
                     const float* __restrict__ bias, float* __restrict__ t1,
                     float* __restrict__ pacc){
  __shared__ float lh[64*64];
  int og = blockIdx.x, sj = blockIdx.y, b = blockIdx.z;
  int tid = threadIdx.x;
  for(int it=0; it<4; ++it){
    int f4 = tid + it*256;               // c*16 + s4
    int c = f4>>4, s4 = f4&15;
    float4 v = *(const float4*)(h + (size_t)(b*64+c)*SPc + sj*64 + s4*4);
    *(float4*)(&lh[c*64 + s4*4]) = v;
  }
  __syncthreads();
  int osub = tid>>6, s = tid&63;
  int ob = og*40 + osub*10;
  float acc[10];
  #pragma unroll
  for(int j=0;j<10;j++) acc[j] = bias[ob+j];
  for(int c=0;c<64;c++){
    float hv = lh[c*64+s];
    #pragma unroll
    for(int j=0;j<10;j++) acc[j] = fmaf(hv, w[(ob+j)*64 + c], acc[j]);
  }
  #pragma unroll
  for(int j=0;j<10;j++){
    int o = ob+j;
    t1[(size_t)(b*320+o)*SPc + sj*64 + s] = acc[j];
    float sm = acc[j], sq = acc[j]*acc[j];
    #pragma unroll
    for(int d=1; d<64; d<<=1){ sm += __shfl_xor(sm,d); sq += __shfl_xor(sq,d); }
    if(s==0){
      pacc[o*128 + b*64 + sj]         = sm;   // P=128
      pacc[40960 + o*128 + b*64 + sj] = sq;   // CP = 320*128
    }
  }
}

// ---- finalize (out-BN only): partials -> A,B ----
__global__ void k_fin(const float* __restrict__ pacc, int P, float invN,
                      const float* __restrict__ g, const float* __restrict__ bb,
                      float* __restrict__ A, float* __restrict__ B){
  __shared__ double sh[256], sh2[256];
  int c = blockIdx.x, C = gridDim.x, tid = threadIdx.x;
  double s=0.0, s2=0.0;
  for(int p=tid; p<P; p+=256){
    s  += (double)pacc[c*P+p];
    s2 += (double)pacc[C*P + c*P + p];
  }
  sh[tid]=s; sh2[tid]=s2; __syncthreads();
  for(int off=128; off>0; off>>=1){
    if(tid<off){ sh[tid]+=sh[tid+off]; sh2[tid]+=sh2[tid+off]; }
    __syncthreads();
  }
  if(tid==0){
    float m = (float)(sh[0]*(double)invN);
    float v = (float)(sh2[0]*(double)invN) - m*m;
    float r = rsqrtf(v + EPSc);
    float gc = g[c];
    A[c] = gc*r;
    B[c] = bb[c] - m*gc*r;
  }
}

// ---- depthwise 3x3; BN1 finalized in prologue; BN2 partials out ----
__global__ void k_dw_s(const float* __restrict__ t1, const float* __restrict__ w,
                       const float* __restrict__ bias, const float* __restrict__ g1,
                       const float* __restrict__ bb1, const float* __restrict__ ap,
                       const float* __restrict__ pin, float* __restrict__ t2,
                       float* __restrict__ pout){
  int tid = threadIdx.x;
  int idx = blockIdx.x*256 + tid;
  int q = idx&63, p=(idx>>6)&63, c=(idx>>12)%C5c, b=idx/(C5c*SPc);
  __shared__ float sAB[2];
  __shared__ float ws4[4];
  {
    float v = (tid<128) ? pin[c*128 + tid] : pin[40960 + c*128 + (tid-128)];
    #pragma unroll
    for(int d=1; d<64; d<<=1) v += __shfl_xor(v, d);
    int wv = tid>>6, ln = tid&63;
    if(ln==0) ws4[wv] = v;
    __syncthreads();
    if(tid==0){
      float S = ws4[0]+ws4[1], Q = ws4[2]+ws4[3];
      float m = S*(1.f/8192.f);
      float var = Q*(1.f/8192.f) - m*m;
      float r = rsqrtf(var + EPSc);
      float gc = g1[c];
      sAB[0] = gc*r; sAB[1] = bb1[c] - m*gc*r;
    }
    __syncthreads();
  }
  float a1 = sAB[0], b1 = sAB[1], al = ap[0];
  const float* ip = t1 + (size_t)(b*C5c+c)*SPc;
  const float* wp = w + c*9;
  float acc = bias[c];
  #pragma unroll
  for(int u=0; u<3; u++){
    int pp = p+u-1; if((unsigned)pp >= 64u) continue;
    #pragma unroll
    for(int v=0; v<3; v++){
      int qq = q+v-1; if((unsigned)qq >= 64u) continue;
      float y = fmaf(ip[pp*64+qq], a1, b1);
      y = y >= 0.f ? y : al*y;
      acc = fmaf(y, wp[u*3+v], acc);
    }
  }
  t2[idx] = acc;
  float sm = acc, sq = acc*acc;
  #pragma unroll
  for(int d=1; d<64; d<<=1){ sm += __shfl_xor(sm,d); sq += __shfl_xor(sq,d); }
  __shared__ float sred[8];
  int wv = tid>>6, ln = tid&63;
  if(ln==0){ sred[wv]=sm; sred[4+wv]=sq; }
  __syncthreads();
  if(tid==0){
    float S = ((sred[0]+sred[1])+(sred[2]+sred[3]));
    float Q = ((sred[4]+sred[5])+(sred[6]+sred[7]));
    int j = blockIdx.x & 15;
    pout[c*32 + b*16 + j]         = S;   // P=32
    pout[10240 + c*32 + b*16 + j] = Q;   // CP = 320*32
  }
}

// ---- full-K 1x1 conv 320->64; BN2 finalized in prologue; BN3 partials out ----
// grid (256 sjf, Bn), 256 thr = 16 og x 16 s. Block: 16 px, all 320 in-ch.
// Input staged in LDS; weights via cached broadcast reads (R12-verified).
__global__ void k_c3f(const float* __restrict__ t2, const float* __restrict__ w,
                      const float* __restrict__ bias, const float* __restrict__ g2,
                      const float* __restrict__ bb2, const float* __restrict__ ap,
                      const float* __restrict__ pin, float* __restrict__ ts,
                      float* __restrict__ pout){
  __shared__ float sA[320], sB[320];
  __shared__ float li[320*16];    // 20 KB
  int sjf = blockIdx.x, b = blockIdx.y;
  int tid = threadIdx.x;
  for(int c = tid; c < 320; c += 256){
    const float4* ps = (const float4*)(pin + c*32);
    const float4* pq = (const float4*)(pin + 10240 + c*32);
    float S=0.f, Q=0.f;
    #pragma unroll
    for(int j=0;j<8;j++){ float4 a = ps[j]; S += ((a.x+a.y)+(a.z+a.w)); }
    #pragma unroll
    for(int j=0;j<8;j++){ float4 a = pq[j]; Q += ((a.x+a.y)+(a.z+a.w)); }
    float m = S*(1.f/8192.f);
    float var = Q*(1.f/8192.f) - m*m;
    float r = rsqrtf(var + EPSc);
    float gc = g2[c];
    sA[c] = gc*r; sB[c] = bb2[c] - m*gc*r;
  }
  __syncthreads();
  float al = ap[0];
  for(int t = tid; t < 1280; t += 256){
    int c = t>>2, k4 = t&3;
    float4 v = *(const float4*)(t2 + (size_t)(b*C5c+c)*SPc + sjf*16 + k4*4);
    float a1 = sA[c], b1 = sB[c];
    float4 y;
    y.x = fmaf(v.x, a1, b1); y.x = y.x>=0.f ? y.x : al*y.x;
    y.y = fmaf(v.y, a1, b1); y.y = y.y>=0.f ? y.y : al*y.y;
    y.z = fmaf(v.z, a1, b1); y.z = y.z>=0.f ? y.z : al*y.z;
    y.w = fmaf(v.w, a1, b1); y.w = y.w>=0.f ? y.w : al*y.w;
    *(float4*)(&li[c*16 + k4*4]) = y;
  }
  __syncthreads();
  int og = tid>>4, s = tid&15;
  float acc[4];
  #pragma unroll
  for(int j=0;j<4;j++) acc[j] = bias[og*4+j];
  const float* wb = w + (size_t)(og*4)*C5c;
  for(int c=0; c<320; c++){
    float hv = li[c*16 + s];
    #pragma unroll
    for(int j=0;j<4;j++)
      acc[j] = fmaf(hv, wb[j*C5c + c], acc[j]);
  }
  #pragma unroll
  for(int j=0;j<4;j++){
    int o = og*4+j;
    ts[(size_t)(b*64+o)*SPc + sjf*16 + s] = acc[j];
    float sm = acc[j], sq = acc[j]*acc[j];
    #pragma unroll
    for(int d=1; d<16; d<<=1){ sm += __shfl_xor(sm,d); sq += __shfl_xor(sq,d); }
    if(s==0){
      pout[o*512 + b*256 + sjf]         = sm;  // P=512
      pout[32768 + o*512 + b*256 + sjf] = sq;  // CP = 64*512
    }
  }
}

// ---- BN3 (finalized in prologue, P=512) + PReLU3 + residual add into h ----
__global__ void k_addres(const float* __restrict__ ts, float* __restrict__ h,
                         const float* __restrict__ g3, const float* __restrict__ bb3,
                         const float* __restrict__ ap, const float* __restrict__ pin){
  int tid = threadIdx.x;
  int idx = blockIdx.x*256 + tid;
  int c = (idx>>12)&63;              // constant per block
  __shared__ float sAB[2];
  __shared__ float w8[8];
  {
    float S = pin[c*512 + tid] + pin[c*512 + 256 + tid];
    float Q = pin[32768 + c*512 + tid] + pin[32768 + c*512 + 256 + tid];
    #pragma unroll
    for(int d=1; d<64; d<<=1){ S += __shfl_xor(S,d); Q += __shfl_xor(Q,d); }
    int wv = tid>>6, ln = tid&63;
    if(ln==0){ w8[wv] = S; w8[4+wv] = Q; }
    __syncthreads();
    if(tid==0){
      float Sa = (w8[0]+w8[1])+(w8[2]+w8[3]);
      float Qa = (w8[4]+w8[5])+(w8[6]+w8[7]);
      float m = Sa*(1.f/8192.f);
      float var = Qa*(1.f/8192.f) - m*m;
      float r = rsqrtf(var + EPSc);
      float gc = g3[c];
      sAB[0] = gc*r; sAB[1] = bb3[c] - m*gc*r;
    }
    __syncthreads();
  }
  float y = fmaf(ts[idx], sAB[0], sAB[1]);
  float al = ap[0];
  y = y >= 0.f ? y : al*y;
  h[idx] += y;
}

// ---- head 1x1 conv (64->512) writing z-innermost gvol, chunk=[k2][o16][z64] ----
__global__ void k_head_t(const float* __restrict__ h, const float* __restrict__ w,
                         const float* __restrict__ bias, float* __restrict__ gv){
  __shared__ float sb0[64*65], sb1[64*65];
  int bid = blockIdx.x;            // (b*16 + o)*16 + ci
  int ci = bid & 15, o = (bid>>4) & 15, b = bid >> 8;
  int c0 = (o*16 + ci)*2, c1 = c0 + 1;
  const float* hp0 = h + (size_t)b*HIDc*SPc;
  const float* w0 = w + (size_t)c0*HIDc;
  const float* w1 = w + (size_t)c1*HIDc;
  float b0 = bias[c0], b1 = bias[c1];
  int tid = threadIdx.x;
  for(int j=0; j<16; j++){
    int s = tid + j*256;           // s = p*64 + q
    float a0 = b0, a1 = b1;
    #pragma unroll 8
    for(int kc=0; kc<HIDc; kc++){
      float hv = hp0[kc*SPc + s];
      a0 = fmaf(hv, w0[kc], a0);
      a1 = fmaf(hv, w1[kc], a1);
    }
    int pad = s + (s>>6);
    sb0[pad] = a0; sb1[pad] = a1;
  }
  __syncthreads();
  float* gb = gv + (size_t)b*(64*16*2048);
  for(int j=0; j<16; j++){
    int t = tid + j*256;
    int q = t>>6, p = t&63;
    size_t base = ((size_t)(q*16 + ci))*2048 + (size_t)o*64 + p;
    gb[base]        = sb0[p*65 + q];   // k=0 weight plane
    gb[base + 1024] = sb1[p*65 + q];   // k=1 bias plane
  }
}

// ---- slice v4: 17-col segments (x0 block-uniform), 1 row/block, 320 thr ----
__global__ void k_slice(const float* __restrict__ x, const float* __restrict__ gv,
                        float* __restrict__ outp, float* __restrict__ pacc){
  __shared__ float lds[8320];     // 4160 float2
  int xseg = blockIdx.x, hp = blockIdx.y, b = blockIdx.z;
  int tid = threadIdx.x;
  const float* gb = gv + (size_t)b*(64*16*2048);
  int y0 = (hp*63)/255;
  int y1 = min(y0+1, 63);
  float fy = hp*(63.f/255.f) - (float)y0;

  if(tid < 128){
    int half = tid & 1, o = (tid>>1)&15, k = (tid>>5)&1, cix = (tid>>6)&1;
    int xs = min(xseg + cix, 15);
    const float* b0p = gb + (size_t)(y0*16+xs)*2048 + k*1024 + o*64;
    const float* b1p = gb + (size_t)(y1*16+xs)*2048 + k*1024 + o*64;
    float2* d = (float2*)lds + cix*2080 + k*1040 + o*65;
    float prev = 0.f;
    if(half){
      float a = b0p[31], c = b1p[31];
      prev = fmaf(fy, c-a, a);
    }
    int j0 = half*8;
    #pragma unroll
    for(int j=0; j<8; ++j){
      int jj = j0 + j;
      float4 a = *(const float4*)(b0p + jj*4);
      float4 c = *(const float4*)(b1p + jj*4);
      float v0 = fmaf(fy, c.x-a.x, a.x);
      float v1 = fmaf(fy, c.y-a.y, a.y);
      float v2 = fmaf(fy, c.z-a.z, a.z);
      float v3 = fmaf(fy, c.w-a.w, a.w);
      if(j > 0 || half) d[4*jj-1] = make_float2(prev, v0);
      d[4*jj]   = make_float2(v0, v1);
      d[4*jj+1] = make_float2(v1, v2);
      d[4*jj+2] = make_float2(v2, v3);
      prev = v3;
    }
    if(half) d[63] = make_float2(prev, prev);
  }
  __syncthreads();

  int wv = tid>>6, lane = tid&63;
  int o = lane>>2, pl = lane&3;
  int lc = wv*4 + pl;               // 0..19 (17+ invalid)
  int wq = xseg*17 + lc;
  bool act = (lc < 17) && (wq < 256);
  int wqc = min(wq, 255);

  float fx = (float)lc * (1.f/17.f);
  float cwA = 1.f - fx, cwB = fx;
  int obase = o*65;
  const float2* l2 = (const float2*)lds;

  float acc = 0.f, bacc = 0.f;
  for(int i=0; i<CIc; i++){
    float xv = x[((size_t)(b*CIc+i)*Hc + hp)*Wc + wqc];
    float g = fminf(fmaxf(xv, 0.f), 1.f);
    float pz = g*63.f;
    int z0 = (int)pz; float fz = pz - (float)z0;
    float wz0 = cwA*(1.f-fz), wz1 = cwA*fz;
    float vz0 = cwB*(1.f-fz), vz1 = cwB*fz;
    int aA = obase + z0, aB = 2080 + obase + z0;
    float2 wA = l2[aA],        wB = l2[aB];
    float2 bA = l2[aA + 1040], bB = l2[aB + 1040];
    float wsum = fmaf(wz0, wA.x, fmaf(wz1, wA.y, fmaf(vz0, wB.x, vz1*wB.y)));
    float bsum = fmaf(wz0, bA.x, fmaf(wz1, bA.y, fmaf(vz0, bB.x, vz1*bB.y)));
    acc  = fmaf(xv, wsum, acc);
    bacc += bsum;
  }
  float vout = act ? (acc + bacc*(1.f/16.f)) : 0.f;
  if(act)
    outp[((size_t)(b*COc+o)*Hc + hp)*Wc + wq] = vout;

  float sm = vout, sq = vout*vout;
  sm += __shfl_xor(sm,1); sq += __shfl_xor(sq,1);
  sm += __shfl_xor(sm,2); sq += __shfl_xor(sq,2);
  __syncthreads();
  if(pl==0){ lds[(wv*16+o)*2] = sm; lds[(wv*16+o)*2+1] = sq; }
  __syncthreads();
  if(tid < 32){
    int oo = tid>>1, kd = tid&1;
    float S = (((lds[(0*16+oo)*2+kd] + lds[(1*16+oo)*2+kd])
             +  (lds[(2*16+oo)*2+kd] + lds[(3*16+oo)*2+kd]))
             +   lds[(4*16+oo)*2+kd]);
    int blk = (b*256 + hp)*16 + xseg;       // P=8192
    pacc[kd*131072 + oo*8192 + blk] = S;    // CP = 16*8192
  }
}

// ---- final BN + SiLU in place on d_out ----
__global__ void k_final(float* __restrict__ out, const float* __restrict__ A,
                        const float* __restrict__ B){
  int idx = blockIdx.x*256 + threadIdx.x;
  int c = (idx>>16)&15;
  float y = fmaf(out[idx], A[c], B[c]);
  out[idx] = y / (1.f + expf(-y));
}

} // namespace

extern "C" void kernel_launch(void* const* d_in, const int* in_sizes, int n_in,
                              void* d_out, int out_size, void* d_ws, size_t ws_size,
                              hipStream_t stream){
  const float* x       = (const float*)d_in[0];
  const float* conv0_w = (const float*)d_in[1];
  const float* conv0_b = (const float*)d_in[2];
  const float* prelu0  = (const float*)d_in[3];
  const float* c1w  = (const float*)d_in[4];
  const float* c1b  = (const float*)d_in[5];
  const float* bn1g = (const float*)d_in[6];
  const float* bn1b = (const float*)d_in[7];
  const float* p1   = (const float*)d_in[8];
  const float* dww  = (const float*)d_in[9];
  const float* dwb  = (const float*)d_in[10];
  const float* bn2g = (const float*)d_in[11];
  const float* bn2b = (const float*)d_in[12];
  const float* p2   = (const float*)d_in[13];
  const float* c3w  = (const float*)d_in[14];
  const float* c3b  = (const float*)d_in[15];
  const float* bn3g = (const float*)d_in[16];
  const float* bn3b = (const float*)d_in[17];
  const float* p3   = (const float*)d_in[18];
  const float* hw   = (const float*)d_in[19];
  const float* hb   = (const float*)d_in[20];
  const float* obg  = (const float*)d_in[21];
  const float* obb  = (const float*)d_in[22];
  float* out = (float*)d_out;
  float* ws  = (float*)d_ws;

  // workspace (floats)
  float* xd    = ws;                 // 131072
  float* h     = xd + 131072;        // 524288
  float* A     = h  + 524288;        // 320
  float* B     = A  + 320;           // 320
  float* pacc  = B  + 320;           // 81920  BN1 partials (k_c1 -> k_dw_s)
  float* paccb = pacc + 81920;       // 20480  BN2 partials (k_dw_s -> k_c3f)
  float* paccc = paccb + 20480;      // 65536  BN3 partials (k_c3f -> k_addres)
  float* t1    = paccc + 65536;      // 2621440
  float* t2    = t1 + 2621440;       // 2621440
  float* ts    = t2 + 2621440;       // 524288
  float* gv    = t1;                 // 4194304 aliases t1+t2 (dead by head)
  float* pacc2 = ts;                 // 262144 slice partials alias ts

  k_down <<<512,  256, 0, stream>>>(x, xd);
  k_conv0<<<2048, 256, 0, stream>>>(xd, conv0_w, conv0_b, prelu0, h);

  for(int i=0; i<3; i++){
    k_c1  <<<dim3(8,64,Bn), 256, 0, stream>>>(h, c1w + i*20480, c1b + i*320, t1, pacc);
    k_dw_s<<<10240, 256, 0, stream>>>(t1, dww + i*2880, dwb + i*320,
                                      bn1g+i*320, bn1b+i*320, p1+i, pacc, t2, paccb);
    k_c3f <<<dim3(256,Bn), 256, 0, stream>>>(t2, c3w + i*20480, c3b + i*64,
                                             bn2g+i*320, bn2b+i*320, p2+i, paccb, ts, paccc);
    k_addres<<<2048, 256, 0, stream>>>(ts, h, bn3g+i*64, bn3b+i*64, p3+i, paccc);
  }

  k_head_t<<<512, 256, 0, stream>>>(h, hw, hb, gv);
  k_slice <<<dim3(16,256,Bn), 320, 0, stream>>>(x, gv, out, pacc2);
  k_fin   <<<16, 256, 0, stream>>>(pacc2, 8192, 1.f/131072.f, obg, obb, A, B);
  k_final <<<8192, 256, 0, stream>>>(out, A, B);
}